// Round 15
// baseline (922.919 us; speedup 1.0000x reference)
//
#include <hip/hip_runtime.h>
#include <cstdint>

typedef unsigned int uint;
typedef unsigned short u16;

#define DEV __device__ __forceinline__

DEV float bf2f(u16 u) { return __uint_as_float(((uint)u) << 16); }
DEV u16 f2bf(float f) {
    uint x = __float_as_uint(f);
    return (u16)((x + 0x7fffu + ((x >> 16) & 1u)) >> 16);
}

struct InPtrs { const void* p[14]; };

// ---------------------------------------------------------------------------
// fused_prep: per-block redundant dtype detect + weight conversion + prep.
// ---------------------------------------------------------------------------
__global__ __launch_bounds__(256) void fused_prep(
    const void* __restrict__ xv, InPtrs ptrs, float* __restrict__ cw,
    float* __restrict__ coorT, float* __restrict__ f0,
    int* __restrict__ flag, int B, int N)
{
    __shared__ int cnt[256];
    __shared__ int sflag;
    const u16* xs = (const u16*)xv;
    int t = threadIdx.x, good = 0;
#pragma unroll
    for (int i = 0; i < 8; ++i) {
        u16 u = xs[(t * 8 + i) * 37];
        int e = (u >> 7) & 0xFF;
        good += (e >= 90 && e <= 150) ? 1 : 0;
    }
    cnt[t] = good;
    __syncthreads();
    if (t == 0) {
        int s = 0;
        for (int i = 0; i < 256; ++i) s += cnt[i];
        sflag = (s >= 1741) ? 1 : 0;
    }
    __syncthreads();
    int isbf = sflag;
    int blk = blockIdx.x;

    if (blk < 128) {
        int p = blk * 256 + t;
        int b = p / N, n = p % N;
        float c0, c1, c2;
        if (isbf) {
            const u16* x = (const u16*)xv;
            c0 = bf2f(x[(b * 3 + 0) * N + n]);
            c1 = bf2f(x[(b * 3 + 1) * N + n]);
            c2 = bf2f(x[(b * 3 + 2) * N + n]);
        } else {
            const float* x = (const float*)xv;
            c0 = x[(b * 3 + 0) * N + n];
            c1 = x[(b * 3 + 1) * N + n];
            c2 = x[(b * 3 + 2) * N + n];
        }
        coorT[p * 3 + 0] = c0; coorT[p * 3 + 1] = c1; coorT[p * 3 + 2] = c2;
        float wl[24], bl[8];
        if (isbf) {
            const u16* wr = (const u16*)ptrs.p[0];
            const u16* br = (const u16*)ptrs.p[1];
#pragma unroll
            for (int i = 0; i < 24; ++i) wl[i] = bf2f(wr[i]);
#pragma unroll
            for (int i = 0; i < 8; ++i) bl[i] = bf2f(br[i]);
        } else {
            const float* wr = (const float*)ptrs.p[0];
            const float* br = (const float*)ptrs.p[1];
#pragma unroll
            for (int i = 0; i < 24; ++i) wl[i] = wr[i];
#pragma unroll
            for (int i = 0; i < 8; ++i) bl[i] = br[i];
        }
#pragma unroll
        for (int o = 0; o < 8; ++o) {
            float v = bl[o];
            v = fmaf(wl[o * 3 + 0], c0, v);
            v = fmaf(wl[o * 3 + 1], c1, v);
            v = fmaf(wl[o * 3 + 2], c2, v);
            f0[(size_t)p * 8 + o] = v;
        }
    } else {
        const int cntb[14] = {24, 8, 512, 32, 32, 4096, 64, 64, 8192, 64, 64, 16384, 128, 128};
        int g = (blk - 128) * 256 + t;
        if (g < 29792) {
            int idx = g, bb = 0;
            while (idx >= cntb[bb]) { idx -= cntb[bb]; ++bb; }
            cw[g] = isbf ? bf2f(((const u16*)ptrs.p[bb])[idx])
                         : ((const float*)ptrs.p[bb])[idx];
        }
        if (blk == 128 && t == 0) flag[0] = isbf;
    }
}

// ---------------------------------------------------------------------------
// shared knn machinery
// ---------------------------------------------------------------------------
#define KNN_INSERT(DV, IV)                                                            \
    if ((DV) < bd[15]) {                                                              \
        _Pragma("unroll")                                                             \
        for (int j = 15; j >= 1; --j) {                                               \
            bool up  = ((DV) < bd[j - 1]);                                            \
            bool chg = ((DV) < bd[j]);                                                \
            if (chg) { bd[j] = up ? bd[j - 1] : (DV); bi[j] = up ? bi[j - 1] : (IV); }\
        }                                                                             \
        if ((DV) < bd[0]) { bd[0] = (DV); bi[0] = (IV); }                             \
    }

#define FPS_DPP_STEP(CTRL)                                                           \
    {                                                                                \
        float ov = __int_as_float(__builtin_amdgcn_update_dpp(                       \
            __float_as_int(bv), __float_as_int(bv), (CTRL), 0xf, 0xf, false));       \
        int oi = __builtin_amdgcn_update_dpp(bid, bid, (CTRL), 0xf, 0xf, false);     \
        bool t = (ov > bv) || (ov == bv && oi < bid);                                \
        bv = t ? ov : bv; bid = t ? oi : bid;                                        \
    }

#define FPS_MRG_STEP(CTRL)                                                           \
    {                                                                                \
        float ov = __int_as_float(__builtin_amdgcn_update_dpp(                       \
            __float_as_int(mv), __float_as_int(mv), (CTRL), 0xf, 0xf, false));       \
        int oi = __builtin_amdgcn_update_dpp(mi, mi, (CTRL), 0xf, 0xf, false);       \
        bool t = (ov > mv) || (ov == mv && oi < mi);                                 \
        mv = t ? ov : mv; mi = t ? oi : mi;                                          \
    }

// ---------------------------------------------------------------------------
// knn_fps_stats1: single-launch concurrency + in-kernel stage-1 fusion.
//  x==0  : fps_big state machine (setprio 3, serial critical path).
//  x>=1  : phase A = knn1 for 64 queries (indices -> idx1 + fin LDS);
//          phase B = stage-1 conv (C_IN=8,C_OUT=32) + GN partials (+vbuf)
//          for the SAME 64 queries -- runs inside the fps block's tail
//          window, removing the standalone stats1 kernel from the critical
//          path. Chunk mapping / sum order identical to the standalone
//          kernel -> stats bit-exact.
// ---------------------------------------------------------------------------
template<int N, int PTS, bool STORE_V>
__global__ __launch_bounds__(256, 2) void knn_fps_stats1_kernel(
    const float* __restrict__ xyz, int* __restrict__ idxout,
    int* __restrict__ fpsout, int npoint,
    const float* __restrict__ f0, const float* __restrict__ w,
    float* __restrict__ partials, float* __restrict__ vbuf)
{
    __shared__ union LU {
        struct {
            float4 kt[256];
            float2 mrg[4][64][16];
            int    fin[64][16];
            float  edge[4][16][16];
            float  gsum[4][4][2];
        } k;
        struct { float4 sxyz[N]; float2 rp[2][4]; } f;
    } u;
    int b = blockIdx.y;
    int tid = threadIdx.x;

    if (blockIdx.x == 0) {
        // ---- fps role ----
        __builtin_amdgcn_s_setprio(3);
        int wave = tid >> 6, lane = tid & 63;
        float px[PTS], py[PTS], pz[PTS], dist[PTS];
#pragma unroll
        for (int i = 0; i < PTS; ++i) {
            int p = tid + i * 256;
            const float* pp = xyz + (size_t)(b * N + p) * 3;
            float x0 = pp[0], y0 = pp[1], z0 = pp[2];
            px[i] = x0; py[i] = y0; pz[i] = z0;
            u.f.sxyz[p] = make_float4(x0, y0, z0, 0.f);
            dist[i] = 1e10f;
        }
        __syncthreads();
        int far = 0;
        int my0 = 0, my1 = 0;
        for (int it = 0; it < npoint; ++it) {
            if (it == tid)       my0 = far;
            if (it == tid + 256) my1 = far;
            float4 cv = u.f.sxyz[far];
            float cx = cv.x, cy = cv.y, cz = cv.z;
            float bv = -1.f; int bid = 0;
#pragma unroll
            for (int i = 0; i < PTS; ++i) {
                float dx = __fsub_rn(px[i], cx);
                float dy = __fsub_rn(py[i], cy);
                float dz = __fsub_rn(pz[i], cz);
                float d = __fadd_rn(__fadd_rn(__fmul_rn(dx, dx), __fmul_rn(dy, dy)), __fmul_rn(dz, dz));
                float nd = fminf(dist[i], d);
                dist[i] = nd;
                bool t = nd > bv;
                bv = t ? nd : bv; bid = t ? (tid + i * 256) : bid;
            }
            FPS_DPP_STEP(0x0B1)
            FPS_DPP_STEP(0x04E)
            FPS_DPP_STEP(0x124)
            FPS_DPP_STEP(0x128)
            FPS_DPP_STEP(0x142)
            FPS_DPP_STEP(0x143)
            int par = it & 1;
            if (lane == 63) u.f.rp[par][wave] = make_float2(bv, __int_as_float(bid));
            __syncthreads();
            {
                float2 e = u.f.rp[par][lane & 3];
                float mv = e.x; int mi = __float_as_int(e.y);
                FPS_MRG_STEP(0x0B1)
                FPS_MRG_STEP(0x04E)
                far = __builtin_amdgcn_readfirstlane(mi);
            }
        }
        __builtin_amdgcn_s_setprio(0);
        if (tid < npoint)       fpsout[b * npoint + tid] = my0;
        if (tid + 256 < npoint) fpsout[b * npoint + tid + 256] = my1;
        return;
    }

    // ---- phase A: knn for queries [(x-1)*64, (x-1)*64+64) ----
    int qloc = tid & 63;
    int wave = tid >> 6;
    int lane = qloc;
    int qbase = (blockIdx.x - 1) * 64;
    int q = qbase + qloc;

    const float* qp = xyz + (size_t)(b * N + q) * 3;
    float qx = qp[0], qy = qp[1], qz = qp[2];
    float qq = __fadd_rn(__fadd_rn(__fmul_rn(qx, qx), __fmul_rn(qy, qy)), __fmul_rn(qz, qz));
    float bd[16]; int bi[16];
#pragma unroll
    for (int j = 0; j < 16; ++j) { bd[j] = 3.4e38f; bi[j] = 0; }
    float cb_d[4]; int cb_i[4]; int cnt = 0;
#pragma unroll
    for (int s = 0; s < 4; ++s) { cb_d[s] = 3.4e38f; cb_i[s] = 0; }

    for (int t0 = 0; t0 < N; t0 += 256) {
        {
            int i = tid;
            const float* kp = xyz + (size_t)(b * N + t0 + i) * 3;
            float kx = kp[0], ky = kp[1], kz = kp[2];
            float kn = __fadd_rn(__fadd_rn(__fmul_rn(kx, kx), __fmul_rn(ky, ky)), __fmul_rn(kz, kz));
            u.k.kt[i] = make_float4(kx, ky, kz, kn);
        }
        __syncthreads();
        for (int i2 = 0; i2 < 64; ++i2) {
            int ii = wave * 64 + i2;
            float4 kv = u.k.kt[ii];
            float dot = __fadd_rn(__fadd_rn(__fmul_rn(qx, kv.x), __fmul_rn(qy, kv.y)),
                                  __fmul_rn(qz, kv.z));
            float d2 = __fsub_rn(__fadd_rn(qq, kv.w), __fmul_rn(2.0f, dot));
            bool adm = (d2 < bd[15]);
            if (adm) {
                int id = t0 + ii;
                cb_d[0] = (cnt == 0) ? d2 : cb_d[0]; cb_i[0] = (cnt == 0) ? id : cb_i[0];
                cb_d[1] = (cnt == 1) ? d2 : cb_d[1]; cb_i[1] = (cnt == 1) ? id : cb_i[1];
                cb_d[2] = (cnt == 2) ? d2 : cb_d[2]; cb_i[2] = (cnt == 2) ? id : cb_i[2];
                cb_d[3] = (cnt == 3) ? d2 : cb_d[3]; cb_i[3] = (cnt == 3) ? id : cb_i[3];
                ++cnt;
            }
            if (__any(cnt >= 4)) {
#pragma unroll
                for (int s = 0; s < 4; ++s) {
                    bool have = s < cnt;
                    float dv = have ? cb_d[s] : 3.4e38f;
                    int   iv = have ? cb_i[s] : 0;
                    KNN_INSERT(dv, iv)
                }
                cnt = 0;
            }
        }
        __syncthreads();
    }
#pragma unroll
    for (int s = 0; s < 4; ++s) {
        bool have = s < cnt;
        float dv = have ? cb_d[s] : 3.4e38f;
        int   iv = have ? cb_i[s] : 0;
        KNN_INSERT(dv, iv)
    }
#pragma unroll
    for (int j = 0; j < 16; ++j)
        u.k.mrg[wave][qloc][j] = make_float2(bd[j], __int_as_float(bi[j]));
    __syncthreads();

    if (tid < 64) {
        int qm = tid;
        int* op = idxout + (size_t)(b * N + qbase + qm) * 16;
        int p0 = 0, p1 = 0, p2 = 0, p3 = 0;
#pragma unroll 1
        for (int j = 0; j < 16; ++j) {
            float2 h0 = u.k.mrg[0][qm][p0], h1 = u.k.mrg[1][qm][p1];
            float2 h2 = u.k.mrg[2][qm][p2], h3 = u.k.mrg[3][qm][p3];
            float bdv = h0.x; int biv = __float_as_int(h0.y); int w_ = 0;
            int i1 = __float_as_int(h1.y);
            if (h1.x < bdv || (h1.x == bdv && i1 < biv)) { bdv = h1.x; biv = i1; w_ = 1; }
            int i2v = __float_as_int(h2.y);
            if (h2.x < bdv || (h2.x == bdv && i2v < biv)) { bdv = h2.x; biv = i2v; w_ = 2; }
            int i3 = __float_as_int(h3.y);
            if (h3.x < bdv || (h3.x == bdv && i3 < biv)) { bdv = h3.x; biv = i3; w_ = 3; }
            op[j] = biv;
            u.k.fin[qm][j] = biv;
            p0 += (w_ == 0); p1 += (w_ == 1); p2 += (w_ == 2); p3 += (w_ == 3);
        }
    }

    // ---- phase B: stage-1 conv + GN partials for the same 64 queries ----
    constexpr int E = 16, GC = 8;
    int nqc = N >> 2;
    for (int it = 0; it < 16; ++it) {
        __syncthreads();   // fin ready (first iter) / edge+gsum consumed (later)
        int ql = it * 4 + wave;          // local query 0..63
        int qg = qbase + ql;
        const float* xqr = f0 + (size_t)(b * N + qg) * 8;
        for (int t = lane; t < 256; t += 64) {
            int k = t >> 4, c = t & 15;
            int j = u.k.fin[ql][k];
            float v;
            if (c < 8) v = f0[(size_t)(b * N + j) * 8 + c] - xqr[c];
            else       v = xqr[c - 8];
            u.k.edge[wave][k][c] = v;
        }
        __syncthreads();
        {
            int oc = lane;
            float s = 0.f, ss = 0.f;
            if (oc < 32) {
                float v[16];
#pragma unroll
                for (int k2 = 0; k2 < 16; ++k2) v[k2] = 0.f;
                const float* wr = w + (size_t)oc * E;
                for (int c = 0; c < E; c += 4) {
                    float4 wv = *reinterpret_cast<const float4*>(wr + c);
#pragma unroll
                    for (int k2 = 0; k2 < 16; ++k2) {
                        const float4 e4 = *reinterpret_cast<const float4*>(&u.k.edge[wave][k2][c]);
                        v[k2] = fmaf(wv.x, e4.x, v[k2]);
                        v[k2] = fmaf(wv.y, e4.y, v[k2]);
                        v[k2] = fmaf(wv.z, e4.z, v[k2]);
                        v[k2] = fmaf(wv.w, e4.w, v[k2]);
                    }
                }
                if (STORE_V) {
                    float4* vb = (float4*)(vbuf + ((size_t)(b * N + qg) * 32 + oc) * 16);
                    vb[0] = make_float4(v[0], v[1], v[2], v[3]);
                    vb[1] = make_float4(v[4], v[5], v[6], v[7]);
                    vb[2] = make_float4(v[8], v[9], v[10], v[11]);
                    vb[3] = make_float4(v[12], v[13], v[14], v[15]);
                }
#pragma unroll
                for (int k2 = 0; k2 < 16; ++k2) { s += v[k2]; ss = fmaf(v[k2], v[k2], ss); }
            }
#pragma unroll
            for (int m2 = 1; m2 < GC; m2 <<= 1) { s += __shfl_xor(s, m2); ss += __shfl_xor(ss, m2); }
            if (oc < 32 && (oc & (GC - 1)) == 0) {
                u.k.gsum[wave][oc / GC][0] = s; u.k.gsum[wave][oc / GC][1] = ss;
            }
        }
        __syncthreads();
        if (tid < 4) {
            int g = tid;
            float s  = ((u.k.gsum[0][g][0] + u.k.gsum[1][g][0]) + u.k.gsum[2][g][0]) + u.k.gsum[3][g][0];
            float ss = ((u.k.gsum[0][g][1] + u.k.gsum[1][g][1]) + u.k.gsum[2][g][1]) + u.k.gsum[3][g][1];
            int chunk = (blockIdx.x - 1) * 16 + it;
            size_t pi = ((size_t)(b * 4 + g) * nqc + chunk) * 2;
            partials[pi] = s; partials[pi + 1] = ss;
        }
    }
}

// ---------------------------------------------------------------------------
// knn_kernel: standard (knn3, knn4).
// ---------------------------------------------------------------------------
__global__ __launch_bounds__(256) void knn_kernel(
    const float* __restrict__ qxyz, const float* __restrict__ kxyz,
    int* __restrict__ idxout, int Nq, int Nk)
{
    __shared__ float4 kt[256];
    __shared__ float2 mrg[4][64][16];
    int b = blockIdx.y;
    int qloc = threadIdx.x & 63;
    int wave = threadIdx.x >> 6;
    int q = blockIdx.x * 64 + qloc;
    bool act = q < Nq;

    float qx = 0.f, qy = 0.f, qz = 0.f, qq = 0.f;
    if (act) {
        const float* qp = qxyz + (size_t)(b * Nq + q) * 3;
        qx = qp[0]; qy = qp[1]; qz = qp[2];
        qq = __fadd_rn(__fadd_rn(__fmul_rn(qx, qx), __fmul_rn(qy, qy)), __fmul_rn(qz, qz));
    }
    float bd[16]; int bi[16];
#pragma unroll
    for (int j = 0; j < 16; ++j) { bd[j] = 3.4e38f; bi[j] = 0; }
    float cb_d[4]; int cb_i[4]; int cnt = 0;
#pragma unroll
    for (int s = 0; s < 4; ++s) { cb_d[s] = 3.4e38f; cb_i[s] = 0; }

    for (int t0 = 0; t0 < Nk; t0 += 256) {
        {
            int i = threadIdx.x;
            const float* kp = kxyz + (size_t)(b * Nk + t0 + i) * 3;
            float kx = kp[0], ky = kp[1], kz = kp[2];
            float kn = __fadd_rn(__fadd_rn(__fmul_rn(kx, kx), __fmul_rn(ky, ky)), __fmul_rn(kz, kz));
            kt[i] = make_float4(kx, ky, kz, kn);
        }
        __syncthreads();
        for (int i2 = 0; i2 < 64; ++i2) {
            int ii = wave * 64 + i2;
            float4 kv = kt[ii];
            float dot = __fadd_rn(__fadd_rn(__fmul_rn(qx, kv.x), __fmul_rn(qy, kv.y)),
                                  __fmul_rn(qz, kv.z));
            float d2 = __fsub_rn(__fadd_rn(qq, kv.w), __fmul_rn(2.0f, dot));
            bool adm = act && (d2 < bd[15]);
            if (adm) {
                int id = t0 + ii;
                cb_d[0] = (cnt == 0) ? d2 : cb_d[0]; cb_i[0] = (cnt == 0) ? id : cb_i[0];
                cb_d[1] = (cnt == 1) ? d2 : cb_d[1]; cb_i[1] = (cnt == 1) ? id : cb_i[1];
                cb_d[2] = (cnt == 2) ? d2 : cb_d[2]; cb_i[2] = (cnt == 2) ? id : cb_i[2];
                cb_d[3] = (cnt == 3) ? d2 : cb_d[3]; cb_i[3] = (cnt == 3) ? id : cb_i[3];
                ++cnt;
            }
            if (__any(cnt >= 4)) {
#pragma unroll
                for (int s = 0; s < 4; ++s) {
                    bool have = s < cnt;
                    float dv = have ? cb_d[s] : 3.4e38f;
                    int   iv = have ? cb_i[s] : 0;
                    KNN_INSERT(dv, iv)
                }
                cnt = 0;
            }
        }
        __syncthreads();
    }
#pragma unroll
    for (int s = 0; s < 4; ++s) {
        bool have = s < cnt;
        float dv = have ? cb_d[s] : 3.4e38f;
        int   iv = have ? cb_i[s] : 0;
        KNN_INSERT(dv, iv)
    }
#pragma unroll
    for (int j = 0; j < 16; ++j)
        mrg[wave][qloc][j] = make_float2(bd[j], __int_as_float(bi[j]));
    __syncthreads();

    if (threadIdx.x < 64) {
        int qm = threadIdx.x;
        int qg = blockIdx.x * 64 + qm;
        if (qg < Nq) {
            int* op = idxout + (size_t)(b * Nq + qg) * 16;
            int p0 = 0, p1 = 0, p2 = 0, p3 = 0;
#pragma unroll 1
            for (int j = 0; j < 16; ++j) {
                float2 h0 = mrg[0][qm][p0], h1 = mrg[1][qm][p1];
                float2 h2 = mrg[2][qm][p2], h3 = mrg[3][qm][p3];
                float bdv = h0.x; int biv = __float_as_int(h0.y); int w_ = 0;
                int i1 = __float_as_int(h1.y);
                if (h1.x < bdv || (h1.x == bdv && i1 < biv)) { bdv = h1.x; biv = i1; w_ = 1; }
                int i2v = __float_as_int(h2.y);
                if (h2.x < bdv || (h2.x == bdv && i2v < biv)) { bdv = h2.x; biv = i2v; w_ = 2; }
                int i3 = __float_as_int(h3.y);
                if (h3.x < bdv || (h3.x == bdv && i3 < biv)) { bdv = h3.x; biv = i3; w_ = 3; }
                op[j] = biv;
                p0 += (w_ == 0); p1 += (w_ == 1); p2 += (w_ == 2); p3 += (w_ == 3);
            }
        }
    }
}

// ---------------------------------------------------------------------------
// knn_part + merge (knn2 key-split x4).
// ---------------------------------------------------------------------------
__global__ __launch_bounds__(256) void knn_part_kernel(
    const float* __restrict__ qxyz, const float* __restrict__ kxyz,
    float2* __restrict__ pbuf, int Nq, int Nk, int nchunk)
{
    __shared__ float4 kt[256];
    __shared__ float2 mrg[4][64][16];
    int qblks = Nq / 64;
    int chunk = blockIdx.x / qblks;
    int qblk = blockIdx.x % qblks;
    int klen = Nk / nchunk;
    int klo = chunk * klen, khi = klo + klen;
    int b = blockIdx.y;
    int qloc = threadIdx.x & 63;
    int wave = threadIdx.x >> 6;
    int q = qblk * 64 + qloc;

    const float* qp = qxyz + (size_t)(b * Nq + q) * 3;
    float qx = qp[0], qy = qp[1], qz = qp[2];
    float qq = __fadd_rn(__fadd_rn(__fmul_rn(qx, qx), __fmul_rn(qy, qy)), __fmul_rn(qz, qz));
    float bd[16]; int bi[16];
#pragma unroll
    for (int j = 0; j < 16; ++j) { bd[j] = 3.4e38f; bi[j] = 0; }
    float cb_d[4]; int cb_i[4]; int cnt = 0;
#pragma unroll
    for (int s = 0; s < 4; ++s) { cb_d[s] = 3.4e38f; cb_i[s] = 0; }

    for (int t0 = klo; t0 < khi; t0 += 256) {
        {
            int i = threadIdx.x;
            const float* kp = kxyz + (size_t)(b * Nk + t0 + i) * 3;
            float kx = kp[0], ky = kp[1], kz = kp[2];
            float kn = __fadd_rn(__fadd_rn(__fmul_rn(kx, kx), __fmul_rn(ky, ky)), __fmul_rn(kz, kz));
            kt[i] = make_float4(kx, ky, kz, kn);
        }
        __syncthreads();
        for (int i2 = 0; i2 < 64; ++i2) {
            int ii = wave * 64 + i2;
            float4 kv = kt[ii];
            float dot = __fadd_rn(__fadd_rn(__fmul_rn(qx, kv.x), __fmul_rn(qy, kv.y)),
                                  __fmul_rn(qz, kv.z));
            float d2 = __fsub_rn(__fadd_rn(qq, kv.w), __fmul_rn(2.0f, dot));
            bool adm = (d2 < bd[15]);
            if (adm) {
                int id = t0 + ii;
                cb_d[0] = (cnt == 0) ? d2 : cb_d[0]; cb_i[0] = (cnt == 0) ? id : cb_i[0];
                cb_d[1] = (cnt == 1) ? d2 : cb_d[1]; cb_i[1] = (cnt == 1) ? id : cb_i[1];
                cb_d[2] = (cnt == 2) ? d2 : cb_d[2]; cb_i[2] = (cnt == 2) ? id : cb_i[2];
                cb_d[3] = (cnt == 3) ? d2 : cb_d[3]; cb_i[3] = (cnt == 3) ? id : cb_i[3];
                ++cnt;
            }
            if (__any(cnt >= 4)) {
#pragma unroll
                for (int s = 0; s < 4; ++s) {
                    bool have = s < cnt;
                    float dv = have ? cb_d[s] : 3.4e38f;
                    int   iv = have ? cb_i[s] : 0;
                    KNN_INSERT(dv, iv)
                }
                cnt = 0;
            }
        }
        __syncthreads();
    }
#pragma unroll
    for (int s = 0; s < 4; ++s) {
        bool have = s < cnt;
        float dv = have ? cb_d[s] : 3.4e38f;
        int   iv = have ? cb_i[s] : 0;
        KNN_INSERT(dv, iv)
    }
#pragma unroll
    for (int j = 0; j < 16; ++j)
        mrg[wave][qloc][j] = make_float2(bd[j], __int_as_float(bi[j]));
    __syncthreads();

    if (threadIdx.x < 64) {
        int qm = threadIdx.x;
        int qg = qblk * 64 + qm;
        float2* op = pbuf + (((size_t)(b * Nq + qg) * nchunk) + chunk) * 16;
        int p0 = 0, p1 = 0, p2 = 0, p3 = 0;
#pragma unroll 1
        for (int j = 0; j < 16; ++j) {
            float2 h0 = mrg[0][qm][p0], h1 = mrg[1][qm][p1];
            float2 h2 = mrg[2][qm][p2], h3 = mrg[3][qm][p3];
            float bdv = h0.x; int biv = __float_as_int(h0.y); int w_ = 0;
            int i1 = __float_as_int(h1.y);
            if (h1.x < bdv || (h1.x == bdv && i1 < biv)) { bdv = h1.x; biv = i1; w_ = 1; }
            int i2v = __float_as_int(h2.y);
            if (h2.x < bdv || (h2.x == bdv && i2v < biv)) { bdv = h2.x; biv = i2v; w_ = 2; }
            int i3 = __float_as_int(h3.y);
            if (h3.x < bdv || (h3.x == bdv && i3 < biv)) { bdv = h3.x; biv = i3; w_ = 3; }
            op[j] = make_float2(bdv, __int_as_float(biv));
            p0 += (w_ == 0); p1 += (w_ == 1); p2 += (w_ == 2); p3 += (w_ == 3);
        }
    }
}

__global__ void knn_merge_kernel(const float2* __restrict__ pbuf, int* __restrict__ idxout,
                                 int total)
{
    int q = blockIdx.x * 256 + threadIdx.x;
    if (q >= total) return;
    const float2* L = pbuf + (size_t)q * 64;
    int* op = idxout + (size_t)q * 16;
    int p0 = 0, p1 = 0, p2 = 0, p3 = 0;
#pragma unroll 1
    for (int j = 0; j < 16; ++j) {
        float2 h0 = L[p0], h1 = L[16 + p1], h2 = L[32 + p2], h3 = L[48 + p3];
        float bdv = h0.x; int biv = __float_as_int(h0.y); int w_ = 0;
        int i1 = __float_as_int(h1.y);
        if (h1.x < bdv || (h1.x == bdv && i1 < biv)) { bdv = h1.x; biv = i1; w_ = 1; }
        int i2v = __float_as_int(h2.y);
        if (h2.x < bdv || (h2.x == bdv && i2v < biv)) { bdv = h2.x; biv = i2v; w_ = 2; }
        int i3 = __float_as_int(h3.y);
        if (h3.x < bdv || (h3.x == bdv && i3 < biv)) { bdv = h3.x; biv = i3; w_ = 3; }
        op[j] = biv;
        p0 += (w_ == 0); p1 += (w_ == 1); p2 += (w_ == 2); p3 += (w_ == 3);
    }
}

// ---------------------------------------------------------------------------
// 5-payload DPP reduce (fps_solo role).
// ---------------------------------------------------------------------------
template<int CTRL>
DEV void red5(float& v, int& i, float& x, float& y, float& z)
{
    float ov = __int_as_float(__builtin_amdgcn_update_dpp(
        __float_as_int(v), __float_as_int(v), CTRL, 0xf, 0xf, false));
    int oi = __builtin_amdgcn_update_dpp(i, i, CTRL, 0xf, 0xf, false);
    float ox = __int_as_float(__builtin_amdgcn_update_dpp(
        __float_as_int(x), __float_as_int(x), CTRL, 0xf, 0xf, false));
    float oy = __int_as_float(__builtin_amdgcn_update_dpp(
        __float_as_int(y), __float_as_int(y), CTRL, 0xf, 0xf, false));
    float oz = __int_as_float(__builtin_amdgcn_update_dpp(
        __float_as_int(z), __float_as_int(z), CTRL, 0xf, 0xf, false));
    bool t = (ov > v) || (ov == v && oi < i);
    v = t ? ov : v; i = t ? oi : i; x = t ? ox : x; y = t ? oy : y; z = t ? oz : z;
}

// ---------------------------------------------------------------------------
// stats3_fps: blockIdx.x==0 -> fps_solo<8,512> role (setprio 3); x>=1 ->
// edge_conv_stats<64,64> with chunk = x-1.
// ---------------------------------------------------------------------------
template<bool STORE_V>
__global__ __launch_bounds__(256) void stats3_fps_kernel(
    const float* __restrict__ fq, const float* __restrict__ fk, const int* __restrict__ idx,
    const float* __restrict__ w, float* __restrict__ partials, float* __restrict__ vbuf,
    const float* __restrict__ fxyz, int* __restrict__ fpsout, int Nq, int Nk)
{
    constexpr int K = 16, C_IN = 64, C_OUT = 64, E = 2 * C_IN, GC = C_OUT / 4;
    __shared__ alignas(16) float edge[4][K][E];
    __shared__ int nidx[4][K];
    __shared__ float gsum[4][4][2];

    int b = blockIdx.y;
    if (blockIdx.x == 0) {
        int tid = threadIdx.x;
        if (tid >= 64) return;
        __builtin_amdgcn_s_setprio(3);
        constexpr int PTS = 8, NL = 512;
        float px[PTS], py[PTS], pz[PTS], dist[PTS];
#pragma unroll
        for (int i = 0; i < PTS; ++i) {
            int p = tid + i * 64;
            const float* pp = fxyz + (size_t)(b * NL + p) * 3;
            px[i] = pp[0]; py[i] = pp[1]; pz[i] = pp[2];
            dist[i] = 1e10f;
        }
        float cx = __int_as_float(__builtin_amdgcn_readlane(__float_as_int(px[0]), 0));
        float cy = __int_as_float(__builtin_amdgcn_readlane(__float_as_int(py[0]), 0));
        float cz = __int_as_float(__builtin_amdgcn_readlane(__float_as_int(pz[0]), 0));
        int curidx = 0;
        int my0 = 0, my1 = 0;
        for (int it = 0; it < 128; ++it) {
            if (it == tid)      my0 = curidx;
            if (it == tid + 64) my1 = curidx;
            float bv = -1.f; int bid = 0; float bx = 0.f, by = 0.f, bz = 0.f;
#pragma unroll
            for (int i = 0; i < PTS; ++i) {
                float dx = __fsub_rn(px[i], cx);
                float dy = __fsub_rn(py[i], cy);
                float dz = __fsub_rn(pz[i], cz);
                float d = __fadd_rn(__fadd_rn(__fmul_rn(dx, dx), __fmul_rn(dy, dy)), __fmul_rn(dz, dz));
                float nd = fminf(dist[i], d);
                dist[i] = nd;
                bool t = nd > bv;
                bv = t ? nd : bv; bid = t ? (tid + i * 64) : bid;
                bx = t ? px[i] : bx; by = t ? py[i] : by; bz = t ? pz[i] : bz;
            }
            red5<0x0B1>(bv, bid, bx, by, bz);
            red5<0x04E>(bv, bid, bx, by, bz);
            red5<0x124>(bv, bid, bx, by, bz);
            red5<0x128>(bv, bid, bx, by, bz);
            red5<0x142>(bv, bid, bx, by, bz);
            red5<0x143>(bv, bid, bx, by, bz);
            curidx = __builtin_amdgcn_readlane(bid, 63);
            cx = __int_as_float(__builtin_amdgcn_readlane(__float_as_int(bx), 63));
            cy = __int_as_float(__builtin_amdgcn_readlane(__float_as_int(by), 63));
            cz = __int_as_float(__builtin_amdgcn_readlane(__float_as_int(bz), 63));
        }
        __builtin_amdgcn_s_setprio(0);
        if (tid < 128)      fpsout[b * 128 + tid] = my0;
        if (tid + 64 < 128) fpsout[b * 128 + tid + 64] = my1;
        return;
    }

    int wave = threadIdx.x >> 6, lane = threadIdx.x & 63;
    int nqc = Nq >> 2;
    int chunk = blockIdx.x - 1;
    int q = chunk * 4 + wave;

    const float* xqr = fq + (size_t)(b * Nq + q) * C_IN;
    if (lane < K) nidx[wave][lane] = idx[(size_t)(b * Nq + q) * K + lane];
    for (int t = lane; t < K * E; t += 64) {
        int k = t / E, c = t % E;
        int j = nidx[wave][k];
        float v;
        if (c < C_IN) v = fk[(size_t)(b * Nk + j) * C_IN + c] - xqr[c];
        else          v = xqr[c - C_IN];
        edge[wave][k][c] = v;
    }
    __syncthreads();

    {
        int oc = lane;
        float s = 0.f, ss = 0.f;
        float v[K];
#pragma unroll
        for (int k2 = 0; k2 < K; ++k2) v[k2] = 0.f;
        const float* wr = w + (size_t)oc * E;
        for (int c = 0; c < E; c += 4) {
            float4 wv = *reinterpret_cast<const float4*>(wr + c);
#pragma unroll
            for (int k2 = 0; k2 < K; ++k2) {
                const float4 e4 = *reinterpret_cast<const float4*>(&edge[wave][k2][c]);
                v[k2] = fmaf(wv.x, e4.x, v[k2]);
                v[k2] = fmaf(wv.y, e4.y, v[k2]);
                v[k2] = fmaf(wv.z, e4.z, v[k2]);
                v[k2] = fmaf(wv.w, e4.w, v[k2]);
            }
        }
        if (STORE_V) {
            float4* vb = (float4*)(vbuf + ((size_t)(b * Nq + q) * C_OUT + oc) * 16);
            vb[0] = make_float4(v[0], v[1], v[2], v[3]);
            vb[1] = make_float4(v[4], v[5], v[6], v[7]);
            vb[2] = make_float4(v[8], v[9], v[10], v[11]);
            vb[3] = make_float4(v[12], v[13], v[14], v[15]);
        }
#pragma unroll
        for (int k2 = 0; k2 < K; ++k2) { s += v[k2]; ss = fmaf(v[k2], v[k2], ss); }
#pragma unroll
        for (int m2 = 1; m2 < GC; m2 <<= 1) { s += __shfl_xor(s, m2); ss += __shfl_xor(ss, m2); }
        if ((oc & (GC - 1)) == 0) {
            gsum[wave][oc / GC][0] = s; gsum[wave][oc / GC][1] = ss;
        }
    }
    __syncthreads();
    if (threadIdx.x < 4) {
        int g = threadIdx.x;
        float s  = ((gsum[0][g][0] + gsum[1][g][0]) + gsum[2][g][0]) + gsum[3][g][0];
        float ss = ((gsum[0][g][1] + gsum[1][g][1]) + gsum[2][g][1]) + gsum[3][g][1];
        size_t pi = ((size_t)(b * 4 + g) * nqc + chunk) * 2;
        partials[pi] = s; partials[pi + 1] = ss;
    }
}

// ---------------------------------------------------------------------------
__global__ void gather_kernel(const float* __restrict__ coorS, const float* __restrict__ fS,
                              const int* __restrict__ fidx, float* __restrict__ coorD,
                              float* __restrict__ fD, int Ns, int M, int C)
{
    int b = blockIdx.y;
    int m = blockIdx.x * blockDim.x + threadIdx.x;
    if (m >= M) return;
    int j = fidx[b * M + m];
#pragma unroll
    for (int c = 0; c < 3; ++c)
        coorD[((size_t)b * M + m) * 3 + c] = coorS[((size_t)b * Ns + j) * 3 + c];
    for (int c = 0; c < C; ++c)
        fD[((size_t)b * M + m) * C + c] = fS[((size_t)b * Ns + j) * C + c];
}

// ---------------------------------------------------------------------------
// edge-conv stats (stages 2, 4 + fallbacks).
// ---------------------------------------------------------------------------
template<int C_IN, int C_OUT, bool STORE_V>
__global__ __launch_bounds__(256) void edge_conv_stats_t(
    const float* __restrict__ fq, const float* __restrict__ fk, const int* __restrict__ idx,
    const float* __restrict__ w, float* __restrict__ partials, float* __restrict__ vbuf,
    int Nq, int Nk)
{
    constexpr int K = 16, E = 2 * C_IN, GC = C_OUT / 4;
    constexpr int ITERS = (C_OUT + 63) / 64;
    __shared__ alignas(16) float edge[4][K][E];
    __shared__ int nidx[4][K];
    __shared__ float gsum[4][4][2];

    int wave = threadIdx.x >> 6, lane = threadIdx.x & 63;
    int nqc = Nq >> 2;
    int b = blockIdx.y, chunk = blockIdx.x;
    int q = chunk * 4 + wave;

    const float* xqr = fq + (size_t)(b * Nq + q) * C_IN;
    if (lane < K) nidx[wave][lane] = idx[(size_t)(b * Nq + q) * K + lane];
    for (int t = lane; t < K * E; t += 64) {
        int k = t / E, c = t % E;
        int j = nidx[wave][k];
        float v;
        if (c < C_IN) v = fk[(size_t)(b * Nk + j) * C_IN + c] - xqr[c];
        else          v = xqr[c - C_IN];
        edge[wave][k][c] = v;
    }
    __syncthreads();

#pragma unroll
    for (int itr = 0; itr < ITERS; ++itr) {
        int oc = lane + 64 * itr;
        float s = 0.f, ss = 0.f;
        if (oc < C_OUT) {
            float v[K];
#pragma unroll
            for (int k2 = 0; k2 < K; ++k2) v[k2] = 0.f;
            const float* wr = w + (size_t)oc * E;
            for (int c = 0; c < E; c += 4) {
                float4 wv = *reinterpret_cast<const float4*>(wr + c);
#pragma unroll
                for (int k2 = 0; k2 < K; ++k2) {
                    const float4 e4 = *reinterpret_cast<const float4*>(&edge[wave][k2][c]);
                    v[k2] = fmaf(wv.x, e4.x, v[k2]);
                    v[k2] = fmaf(wv.y, e4.y, v[k2]);
                    v[k2] = fmaf(wv.z, e4.z, v[k2]);
                    v[k2] = fmaf(wv.w, e4.w, v[k2]);
                }
            }
            if (STORE_V) {
                float4* vb = (float4*)(vbuf + ((size_t)(b * Nq + q) * C_OUT + oc) * 16);
                vb[0] = make_float4(v[0], v[1], v[2], v[3]);
                vb[1] = make_float4(v[4], v[5], v[6], v[7]);
                vb[2] = make_float4(v[8], v[9], v[10], v[11]);
                vb[3] = make_float4(v[12], v[13], v[14], v[15]);
            }
#pragma unroll
            for (int k2 = 0; k2 < K; ++k2) { s += v[k2]; ss = fmaf(v[k2], v[k2], ss); }
        }
#pragma unroll
        for (int m2 = 1; m2 < GC; m2 <<= 1) { s += __shfl_xor(s, m2); ss += __shfl_xor(ss, m2); }
        if (oc < C_OUT && (oc & (GC - 1)) == 0) {
            gsum[wave][oc / GC][0] = s; gsum[wave][oc / GC][1] = ss;
        }
    }
    __syncthreads();
    if (threadIdx.x < 4) {
        int g = threadIdx.x;
        float s  = ((gsum[0][g][0] + gsum[1][g][0]) + gsum[2][g][0]) + gsum[3][g][0];
        float ss = ((gsum[0][g][1] + gsum[1][g][1]) + gsum[2][g][1]) + gsum[3][g][1];
        size_t pi = ((size_t)(b * 4 + g) * nqc + chunk) * 2;
        partials[pi] = s; partials[pi + 1] = ss;
    }
}

__global__ void gn_finalize(const float* __restrict__ partials, float* __restrict__ stats,
                            int nchunk, float inv_cnt)
{
    int i = threadIdx.x >> 3;
    int sl = threadIdx.x & 7;
    float s = 0.f, ss = 0.f;
    for (int c = sl; c < nchunk; c += 8) {
        s  += partials[((size_t)i * nchunk + c) * 2];
        ss += partials[((size_t)i * nchunk + c) * 2 + 1];
    }
#pragma unroll
    for (int m = 1; m < 8; m <<= 1) { s += __shfl_xor(s, m); ss += __shfl_xor(ss, m); }
    if (sl == 0) {
        float mean = s * inv_cnt;
        float var = fmaf(-mean, mean, ss * inv_cnt);
        stats[i * 2] = mean;
        stats[i * 2 + 1] = 1.0f / sqrtf(var + 1e-5f);
    }
}

// ---------------------------------------------------------------------------
// apply (fallback: recompute conv).
// ---------------------------------------------------------------------------
template<int C_IN, int C_OUT>
__global__ __launch_bounds__(256) void edge_conv_apply(
    const float* __restrict__ fq, const float* __restrict__ fk, const int* __restrict__ idx,
    const float* __restrict__ stats, const float* __restrict__ w,
    const float* __restrict__ gamma, const float* __restrict__ beta,
    float* __restrict__ outp, int Nq, int Nk)
{
    constexpr int K = 16, E = 2 * C_IN, GC = C_OUT / 4;
    constexpr int ITERS = (C_OUT + 63) / 64;
    __shared__ alignas(16) float edge[4][K][E];
    __shared__ int nidx[4][K];

    int wave = threadIdx.x >> 6, lane = threadIdx.x & 63;
    int b = blockIdx.y, chunk = blockIdx.x;
    int q = chunk * 4 + wave;

    const float* xqr = fq + (size_t)(b * Nq + q) * C_IN;
    if (lane < K) nidx[wave][lane] = idx[(size_t)(b * Nq + q) * K + lane];
    for (int t = lane; t < K * E; t += 64) {
        int k = t / E, c = t % E;
        int j = nidx[wave][k];
        float v;
        if (c < C_IN) v = fk[(size_t)(b * Nk + j) * C_IN + c] - xqr[c];
        else          v = xqr[c - C_IN];
        edge[wave][k][c] = v;
    }
    __syncthreads();

#pragma unroll
    for (int itr = 0; itr < ITERS; ++itr) {
        int oc = lane + 64 * itr;
        if (oc < C_OUT) {
            float v[K];
#pragma unroll
            for (int k2 = 0; k2 < K; ++k2) v[k2] = 0.f;
            const float* wr = w + (size_t)oc * E;
            for (int c = 0; c < E; c += 4) {
                float4 wv = *reinterpret_cast<const float4*>(wr + c);
#pragma unroll
                for (int k2 = 0; k2 < K; ++k2) {
                    const float4 e4 = *reinterpret_cast<const float4*>(&edge[wave][k2][c]);
                    v[k2] = fmaf(wv.x, e4.x, v[k2]);
                    v[k2] = fmaf(wv.y, e4.y, v[k2]);
                    v[k2] = fmaf(wv.z, e4.z, v[k2]);
                    v[k2] = fmaf(wv.w, e4.w, v[k2]);
                }
            }
            int g = oc / GC;
            float mean = stats[(b * 4 + g) * 2 + 0];
            float rstd = stats[(b * 4 + g) * 2 + 1];
            float ga = gamma[oc], be = beta[oc];
            float m = -3.4e38f;
#pragma unroll
            for (int k2 = 0; k2 < K; ++k2) {
                float y = fmaf((v[k2] - mean) * rstd, ga, be);
                y = (y >= 0.f) ? y : 0.2f * y;
                m = fmaxf(m, y);
            }
            outp[(size_t)(b * Nq + q) * C_OUT + oc] = m;
        }
    }
}

// ---------------------------------------------------------------------------
template<int C_OUT>
__global__ __launch_bounds__(256) void edge_conv_apply2(
    const float* __restrict__ vbuf, const float* __restrict__ stats,
    const float* __restrict__ gamma, const float* __restrict__ beta,
    float* __restrict__ outp, int total, int Nq)
{
    constexpr int GC = C_OUT / 4;
    int t = blockIdx.x * 256 + threadIdx.x;
    if (t >= total) return;
    int oc = t & (C_OUT - 1);
    int bq = t / C_OUT;
    int b = bq / Nq;
    int g = oc / GC;
    float mean = stats[(b * 4 + g) * 2 + 0];
    float rstd = stats[(b * 4 + g) * 2 + 1];
    float ga = gamma[oc], be = beta[oc];
    const float4* vb = (const float4*)(vbuf + (size_t)t * 16);
    float m = -3.4e38f;
#pragma unroll
    for (int j = 0; j < 4; ++j) {
        float4 v4 = vb[j];
        float y;
        y = fmaf((v4.x - mean) * rstd, ga, be); y = (y >= 0.f) ? y : 0.2f * y; m = fmaxf(m, y);
        y = fmaf((v4.y - mean) * rstd, ga, be); y = (y >= 0.f) ? y : 0.2f * y; m = fmaxf(m, y);
        y = fmaf((v4.z - mean) * rstd, ga, be); y = (y >= 0.f) ? y : 0.2f * y; m = fmaxf(m, y);
        y = fmaf((v4.w - mean) * rstd, ga, be); y = (y >= 0.f) ? y : 0.2f * y; m = fmaxf(m, y);
    }
    outp[t] = m;
}

// ---------------------------------------------------------------------------
__global__ __launch_bounds__(256) void apply2_out(
    const float* __restrict__ vbuf, const float* __restrict__ stats,
    const float* __restrict__ gamma, const float* __restrict__ beta,
    const float* __restrict__ coor2T, void* __restrict__ outv,
    const int* __restrict__ flag)
{
    int t = blockIdx.x * 256 + threadIdx.x;
    int isbf = flag[0];
    if (t < 131072) {
        int oc = t & 127;
        int bq = t >> 7;
        int b = bq >> 7;
        int q = bq & 127;
        int g = oc >> 5;
        float mean = stats[(b * 4 + g) * 2 + 0];
        float rstd = stats[(b * 4 + g) * 2 + 1];
        float ga = gamma[oc], be = beta[oc];
        const float4* vb = (const float4*)(vbuf + (size_t)t * 16);
        float m = -3.4e38f;
#pragma unroll
        for (int j = 0; j < 4; ++j) {
            float4 v4 = vb[j];
            float y;
            y = fmaf((v4.x - mean) * rstd, ga, be); y = (y >= 0.f) ? y : 0.2f * y; m = fmaxf(m, y);
            y = fmaf((v4.y - mean) * rstd, ga, be); y = (y >= 0.f) ? y : 0.2f * y; m = fmaxf(m, y);
            y = fmaf((v4.z - mean) * rstd, ga, be); y = (y >= 0.f) ? y : 0.2f * y; m = fmaxf(m, y);
            y = fmaf((v4.w - mean) * rstd, ga, be); y = (y >= 0.f) ? y : 0.2f * y; m = fmaxf(m, y);
        }
        int i = 3072 + b * 16384 + oc * 128 + q;
        if (isbf) ((u16*)outv)[i] = f2bf(m);
        else      ((float*)outv)[i] = m;
    } else if (t < 134144) {
        int i = t - 131072;
        int b = i / 384, r = i % 384;
        int c = r / 128, n = r % 128;
        float v = coor2T[((size_t)b * 128 + n) * 3 + c];
        if (isbf) ((u16*)outv)[i] = f2bf(v);
        else      ((float*)outv)[i] = v;
    }
}

// ---------------------------------------------------------------------------
__global__ void write_out_kernel(const float* __restrict__ coor2T, const float* __restrict__ f4T,
                                 void* __restrict__ outv, const int* __restrict__ flag)
{
    int i = blockIdx.x * blockDim.x + threadIdx.x;
    if (i >= 134144) return;
    float v;
    if (i < 3072) {
        int b = i / 384, r = i % 384;
        int c = r / 128, n = r % 128;
        v = coor2T[((size_t)b * 128 + n) * 3 + c];
    } else {
        int jj = i - 3072;
        int b = jj / 16384, r = jj % 16384;
        int c = r / 128, qn = r % 128;
        v = f4T[((size_t)b * 128 + qn) * 128 + c];
    }
    if (flag[0]) ((u16*)outv)[i] = f2bf(v);
    else         ((float*)outv)[i] = v;
}

// ---------------------------------------------------------------------------
extern "C" void kernel_launch(void* const* d_in, const int* in_sizes, int n_in,
                              void* d_out, int out_size, void* d_ws, size_t ws_size,
                              hipStream_t stream)
{
    (void)in_sizes; (void)n_in; (void)out_size;
    constexpr int B = 8, N = 4096, M1 = 512, M2 = 128;

    float* fbase   = (float*)d_ws;
    float* coorT   = fbase;                  // 98304
    float* f0T     = coorT + 98304;          // 262144
    float* f1T     = f0T + 262144;           // 1048576
    float* f2T     = f1T + 1048576;          // 262144
    float* f3T     = f2T + 262144;           // 262144
    float* f4T     = f3T + 262144;           // 131072
    float* coor1T  = f4T + 131072;           // 12288
    float* coor2T  = coor1T + 12288;         // 3072
    float* fq2T    = coor2T + 3072;          // 131072
    float* fq4T    = fq2T + 131072;          // 65536
    float* statsb  = fq4T + 65536;           // 256
    float* partials= statsb + 256;           // 65536
    float* pb      = partials + 65536;       // 524288
    float* cw      = pb + 524288;            // 29792 (+pad)
    int* ibase = (int*)(cw + 29796);
    int* idx1 = ibase;                       // 524288
    int* idx2 = idx1 + 524288;               // 65536
    int* idx3 = idx2 + 65536;                // 65536
    int* idx4 = idx3 + 65536;                // 16384
    int* fps1 = idx4 + 16384;                // 4096
    int* fps2 = fps1 + 4096;                 // 1024
    int* flag = fps2 + 1024;                 // 1

    size_t used = (size_t)((char*)(flag + 1) - (char*)d_ws);
    size_t voff = (used + 255) & ~(size_t)255;
    float* vbuf = (float*)((char*)d_ws + voff);
    bool fu1 = ws_size >= voff + (size_t)16777216 * 4;
    bool fu2 = ws_size >= voff + (size_t)4194304 * 4;
    bool fu3 = fu2;
    bool fu4 = ws_size >= voff + (size_t)2097152 * 4;

    const float* w1c  = cw + 32;
    const float* g1c  = cw + 544;
    const float* be1c = cw + 576;
    const float* w2c  = cw + 608;
    const float* g2c  = cw + 4704;
    const float* be2c = cw + 4768;
    const float* w3c  = cw + 4832;
    const float* g3c  = cw + 13024;
    const float* be3c = cw + 13088;
    const float* w4c  = cw + 13152;
    const float* g4c  = cw + 29536;
    const float* be4c = cw + 29664;

    InPtrs ptrs;
    for (int i = 0; i < 14; ++i) ptrs.p[i] = d_in[i + 2];

    fused_prep<<<245, 256, 0, stream>>>(d_in[0], ptrs, cw, coorT, f0T, flag, B, N);

    // stage 1: ONE launch = fps_big (x==0, setprio 3) || knn1+stats1 fused
    if (fu1) {
        knn_fps_stats1_kernel<4096, 16, true><<<dim3(N / 64 + 1, B), 256, 0, stream>>>(
            coorT, idx1, fps1, M1, f0T, w1c, partials, vbuf);
        gn_finalize<<<1, 256, 0, stream>>>(partials, statsb + 0, N / 4, 1.0f / (float)(N * 16 * 8));
        edge_conv_apply2<32><<<(B * N * 32 + 255) / 256, 256, 0, stream>>>(vbuf, statsb + 0, g1c, be1c, f1T, B * N * 32, N);
    } else {
        knn_fps_stats1_kernel<4096, 16, false><<<dim3(N / 64 + 1, B), 256, 0, stream>>>(
            coorT, idx1, fps1, M1, f0T, w1c, partials, vbuf);
        gn_finalize<<<1, 256, 0, stream>>>(partials, statsb + 0, N / 4, 1.0f / (float)(N * 16 * 8));
        edge_conv_apply<8, 32><<<dim3(N / 4, B), 256, 0, stream>>>(f0T, f0T, idx1, statsb + 0, w1c, g1c, be1c, f1T, N, N);
    }
    gather_kernel<<<dim3((M1 + 255) / 256, B), 256, 0, stream>>>(coorT, f1T, fps1, coor1T, fq2T, N, M1, 32);

    // stage 2: knn2 split into 4 key-chunks + merge
    knn_part_kernel<<<dim3((M1 / 64) * 4, B), 256, 0, stream>>>(coor1T, coorT, (float2*)pb, M1, N, 4);
    knn_merge_kernel<<<(B * M1 + 255) / 256, 256, 0, stream>>>((const float2*)pb, idx2, B * M1);
    if (fu2) {
        edge_conv_stats_t<32, 64, true><<<dim3(M1 / 4, B), 256, 0, stream>>>(fq2T, f1T, idx2, w2c, partials, vbuf, M1, N);
        gn_finalize<<<1, 256, 0, stream>>>(partials, statsb + 64, M1 / 4, 1.0f / (float)(M1 * 16 * 16));
        edge_conv_apply2<64><<<(B * M1 * 64 + 255) / 256, 256, 0, stream>>>(vbuf, statsb + 64, g2c, be2c, f2T, B * M1 * 64, M1);
    } else {
        edge_conv_stats_t<32, 64, false><<<dim3(M1 / 4, B), 256, 0, stream>>>(fq2T, f1T, idx2, w2c, partials, vbuf, M1, N);
        gn_finalize<<<1, 256, 0, stream>>>(partials, statsb + 64, M1 / 4, 1.0f / (float)(M1 * 16 * 16));
        edge_conv_apply<32, 64><<<dim3(M1 / 4, B), 256, 0, stream>>>(fq2T, f1T, idx2, statsb + 64, w2c, g2c, be2c, f2T, M1, N);
    }

    // stage 3: knn3, then stats3 || fps_solo (setprio 3)
    knn_kernel<<<dim3(M1 / 64, B), 256, 0, stream>>>(coor1T, coor1T, idx3, M1, M1);
    if (fu3) {
        stats3_fps_kernel<true><<<dim3(M1 / 4 + 1, B), 256, 0, stream>>>(
            f2T, f2T, idx3, w3c, partials, vbuf, coor1T, fps2, M1, M1);
        gn_finalize<<<1, 256, 0, stream>>>(partials, statsb + 128, M1 / 4, 1.0f / (float)(M1 * 16 * 16));
        edge_conv_apply2<64><<<(B * M1 * 64 + 255) / 256, 256, 0, stream>>>(vbuf, statsb + 128, g3c, be3c, f3T, B * M1 * 64, M1);
    } else {
        stats3_fps_kernel<false><<<dim3(M1 / 4 + 1, B), 256, 0, stream>>>(
            f2T, f2T, idx3, w3c, partials, vbuf, coor1T, fps2, M1, M1);
        gn_finalize<<<1, 256, 0, stream>>>(partials, statsb + 128, M1 / 4, 1.0f / (float)(M1 * 16 * 16));
        edge_conv_apply<64, 64><<<dim3(M1 / 4, B), 256, 0, stream>>>(f2T, f2T, idx3, statsb + 128, w3c, g3c, be3c, f3T, M1, M1);
    }
    gather_kernel<<<dim3(1, B), 256, 0, stream>>>(coor1T, f3T, fps2, coor2T, fq4T, M1, M2, 64);

    // stage 4
    knn_kernel<<<dim3((M2 + 63) / 64, B), 256, 0, stream>>>(coor2T, coor1T, idx4, M2, M1);
    if (fu4) {
        edge_conv_stats_t<64, 128, true><<<dim3(M2 / 4, B), 256, 0, stream>>>(fq4T, f3T, idx4, w4c, partials, vbuf, M2, M1);
        gn_finalize<<<1, 256, 0, stream>>>(partials, statsb + 192, M2 / 4, 1.0f / (float)(M2 * 16 * 32));
        apply2_out<<<(134144 + 255) / 256, 256, 0, stream>>>(vbuf, statsb + 192, g4c, be4c, coor2T, d_out, flag);
    } else {
        edge_conv_stats_t<64, 128, false><<<dim3(M2 / 4, B), 256, 0, stream>>>(fq4T, f3T, idx4, w4c, partials, vbuf, M2, M1);
        gn_finalize<<<1, 256, 0, stream>>>(partials, statsb + 192, M2 / 4, 1.0f / (float)(M2 * 16 * 32));
        edge_conv_apply<64, 128><<<dim3(M2 / 4, B), 256, 0, stream>>>(fq4T, f3T, idx4, statsb + 192, w4c, g4c, be4c, f4T, M2, M1);
        write_out_kernel<<<(134144 + 255) / 256, 256, 0, stream>>>(coor2T, f4T, d_out, flag);
    }
}

// Round 16
// 851.960 us; speedup vs baseline: 1.0833x; 1.0833x over previous
//
#include <hip/hip_runtime.h>
#include <cstdint>

typedef unsigned int uint;
typedef unsigned short u16;

#define DEV __device__ __forceinline__

DEV float bf2f(u16 u) { return __uint_as_float(((uint)u) << 16); }
DEV u16 f2bf(float f) {
    uint x = __float_as_uint(f);
    return (u16)((x + 0x7fffu + ((x >> 16) & 1u)) >> 16);
}

struct InPtrs { const void* p[14]; };

// ---------------------------------------------------------------------------
// fused_prep: per-block redundant dtype detect + weight conversion + prep.
// ---------------------------------------------------------------------------
__global__ __launch_bounds__(256) void fused_prep(
    const void* __restrict__ xv, InPtrs ptrs, float* __restrict__ cw,
    float* __restrict__ coorT, float* __restrict__ f0,
    int* __restrict__ flag, int B, int N)
{
    __shared__ int cnt[256];
    __shared__ int sflag;
    const u16* xs = (const u16*)xv;
    int t = threadIdx.x, good = 0;
#pragma unroll
    for (int i = 0; i < 8; ++i) {
        u16 u = xs[(t * 8 + i) * 37];
        int e = (u >> 7) & 0xFF;
        good += (e >= 90 && e <= 150) ? 1 : 0;
    }
    cnt[t] = good;
    __syncthreads();
    if (t == 0) {
        int s = 0;
        for (int i = 0; i < 256; ++i) s += cnt[i];
        sflag = (s >= 1741) ? 1 : 0;
    }
    __syncthreads();
    int isbf = sflag;
    int blk = blockIdx.x;

    if (blk < 128) {
        int p = blk * 256 + t;
        int b = p / N, n = p % N;
        float c0, c1, c2;
        if (isbf) {
            const u16* x = (const u16*)xv;
            c0 = bf2f(x[(b * 3 + 0) * N + n]);
            c1 = bf2f(x[(b * 3 + 1) * N + n]);
            c2 = bf2f(x[(b * 3 + 2) * N + n]);
        } else {
            const float* x = (const float*)xv;
            c0 = x[(b * 3 + 0) * N + n];
            c1 = x[(b * 3 + 1) * N + n];
            c2 = x[(b * 3 + 2) * N + n];
        }
        coorT[p * 3 + 0] = c0; coorT[p * 3 + 1] = c1; coorT[p * 3 + 2] = c2;
        float wl[24], bl[8];
        if (isbf) {
            const u16* wr = (const u16*)ptrs.p[0];
            const u16* br = (const u16*)ptrs.p[1];
#pragma unroll
            for (int i = 0; i < 24; ++i) wl[i] = bf2f(wr[i]);
#pragma unroll
            for (int i = 0; i < 8; ++i) bl[i] = bf2f(br[i]);
        } else {
            const float* wr = (const float*)ptrs.p[0];
            const float* br = (const float*)ptrs.p[1];
#pragma unroll
            for (int i = 0; i < 24; ++i) wl[i] = wr[i];
#pragma unroll
            for (int i = 0; i < 8; ++i) bl[i] = br[i];
        }
#pragma unroll
        for (int o = 0; o < 8; ++o) {
            float v = bl[o];
            v = fmaf(wl[o * 3 + 0], c0, v);
            v = fmaf(wl[o * 3 + 1], c1, v);
            v = fmaf(wl[o * 3 + 2], c2, v);
            f0[(size_t)p * 8 + o] = v;
        }
    } else {
        const int cntb[14] = {24, 8, 512, 32, 32, 4096, 64, 64, 8192, 64, 64, 16384, 128, 128};
        int g = (blk - 128) * 256 + t;
        if (g < 29792) {
            int idx = g, bb = 0;
            while (idx >= cntb[bb]) { idx -= cntb[bb]; ++bb; }
            cw[g] = isbf ? bf2f(((const u16*)ptrs.p[bb])[idx])
                         : ((const float*)ptrs.p[bb])[idx];
        }
        if (blk == 128 && t == 0) flag[0] = isbf;
    }
}

// ---------------------------------------------------------------------------
// shared knn machinery
// ---------------------------------------------------------------------------
#define KNN_INSERT(DV, IV)                                                            \
    if ((DV) < bd[15]) {                                                              \
        _Pragma("unroll")                                                             \
        for (int j = 15; j >= 1; --j) {                                               \
            bool up  = ((DV) < bd[j - 1]);                                            \
            bool chg = ((DV) < bd[j]);                                                \
            if (chg) { bd[j] = up ? bd[j - 1] : (DV); bi[j] = up ? bi[j - 1] : (IV); }\
        }                                                                             \
        if ((DV) < bd[0]) { bd[0] = (DV); bi[0] = (IV); }                             \
    }

#define FPS_DPP_STEP(CTRL)                                                           \
    {                                                                                \
        float ov = __int_as_float(__builtin_amdgcn_update_dpp(                       \
            __float_as_int(bv), __float_as_int(bv), (CTRL), 0xf, 0xf, false));       \
        int oi = __builtin_amdgcn_update_dpp(bid, bid, (CTRL), 0xf, 0xf, false);     \
        bool t = (ov > bv) || (ov == bv && oi < bid);                                \
        bv = t ? ov : bv; bid = t ? oi : bid;                                        \
    }

#define FPS_MRG_STEP(CTRL)                                                           \
    {                                                                                \
        float ov = __int_as_float(__builtin_amdgcn_update_dpp(                       \
            __float_as_int(mv), __float_as_int(mv), (CTRL), 0xf, 0xf, false));       \
        int oi = __builtin_amdgcn_update_dpp(mi, mi, (CTRL), 0xf, 0xf, false);       \
        bool t = (ov > mv) || (ov == mv && oi < mi);                                 \
        mv = t ? ov : mv; mi = t ? oi : mi;                                          \
    }

// ---------------------------------------------------------------------------
// knn_fps: single-launch concurrency. blockIdx.x==0 runs the fps_big state
// machine (s_setprio(3): serial critical path, co-resident with throughput
// knn waves -- T5 regime, measured -45us in r14); x>=1 run knn1 (Nq=Nk=N).
// LDS = union(knn 36KB, fps 64.1KB); (256,2) caps VGPR at 128 (fps needs 88).
// ---------------------------------------------------------------------------
template<int N, int PTS>
__global__ __launch_bounds__(256, 2) void knn_fps_kernel(
    const float* __restrict__ xyz, int* __restrict__ idxout,
    int* __restrict__ fpsout, int npoint)
{
    __shared__ union LU {
        struct { float4 kt[256]; float2 mrg[4][64][16]; } k;
        struct { float4 sxyz[N]; float2 rp[2][4]; } f;
    } u;
    int b = blockIdx.y;
    int tid = threadIdx.x;

    if (blockIdx.x == 0) {
        // ---- fps role ----
        __builtin_amdgcn_s_setprio(3);
        int wave = tid >> 6, lane = tid & 63;
        float px[PTS], py[PTS], pz[PTS], dist[PTS];
#pragma unroll
        for (int i = 0; i < PTS; ++i) {
            int p = tid + i * 256;
            const float* pp = xyz + (size_t)(b * N + p) * 3;
            float x0 = pp[0], y0 = pp[1], z0 = pp[2];
            px[i] = x0; py[i] = y0; pz[i] = z0;
            u.f.sxyz[p] = make_float4(x0, y0, z0, 0.f);
            dist[i] = 1e10f;
        }
        __syncthreads();
        int far = 0;
        int my0 = 0, my1 = 0;
        for (int it = 0; it < npoint; ++it) {
            if (it == tid)       my0 = far;
            if (it == tid + 256) my1 = far;
            float4 cv = u.f.sxyz[far];
            float cx = cv.x, cy = cv.y, cz = cv.z;
            float bv = -1.f; int bid = 0;
#pragma unroll
            for (int i = 0; i < PTS; ++i) {
                float dx = __fsub_rn(px[i], cx);
                float dy = __fsub_rn(py[i], cy);
                float dz = __fsub_rn(pz[i], cz);
                float d = __fadd_rn(__fadd_rn(__fmul_rn(dx, dx), __fmul_rn(dy, dy)), __fmul_rn(dz, dz));
                float nd = fminf(dist[i], d);
                dist[i] = nd;
                bool t = nd > bv;
                bv = t ? nd : bv; bid = t ? (tid + i * 256) : bid;
            }
            FPS_DPP_STEP(0x0B1)
            FPS_DPP_STEP(0x04E)
            FPS_DPP_STEP(0x124)
            FPS_DPP_STEP(0x128)
            FPS_DPP_STEP(0x142)
            FPS_DPP_STEP(0x143)
            int par = it & 1;
            if (lane == 63) u.f.rp[par][wave] = make_float2(bv, __int_as_float(bid));
            __syncthreads();
            {
                float2 e = u.f.rp[par][lane & 3];
                float mv = e.x; int mi = __float_as_int(e.y);
                FPS_MRG_STEP(0x0B1)
                FPS_MRG_STEP(0x04E)
                far = __builtin_amdgcn_readfirstlane(mi);
            }
        }
        __builtin_amdgcn_s_setprio(0);
        if (tid < npoint)       fpsout[b * npoint + tid] = my0;
        if (tid + 256 < npoint) fpsout[b * npoint + tid + 256] = my1;
        return;
    }

    // ---- knn role (Nq=Nk=N, q-block = blockIdx.x-1) ----
    int qloc = tid & 63;
    int wave = tid >> 6;
    int q = (blockIdx.x - 1) * 64 + qloc;

    const float* qp = xyz + (size_t)(b * N + q) * 3;
    float qx = qp[0], qy = qp[1], qz = qp[2];
    float qq = __fadd_rn(__fadd_rn(__fmul_rn(qx, qx), __fmul_rn(qy, qy)), __fmul_rn(qz, qz));
    float bd[16]; int bi[16];
#pragma unroll
    for (int j = 0; j < 16; ++j) { bd[j] = 3.4e38f; bi[j] = 0; }
    float cb_d[4]; int cb_i[4]; int cnt = 0;
#pragma unroll
    for (int s = 0; s < 4; ++s) { cb_d[s] = 3.4e38f; cb_i[s] = 0; }

    for (int t0 = 0; t0 < N; t0 += 256) {
        {
            int i = tid;
            const float* kp = xyz + (size_t)(b * N + t0 + i) * 3;
            float kx = kp[0], ky = kp[1], kz = kp[2];
            float kn = __fadd_rn(__fadd_rn(__fmul_rn(kx, kx), __fmul_rn(ky, ky)), __fmul_rn(kz, kz));
            u.k.kt[i] = make_float4(kx, ky, kz, kn);
        }
        __syncthreads();
        for (int i2 = 0; i2 < 64; ++i2) {
            int ii = wave * 64 + i2;
            float4 kv = u.k.kt[ii];
            float dot = __fadd_rn(__fadd_rn(__fmul_rn(qx, kv.x), __fmul_rn(qy, kv.y)),
                                  __fmul_rn(qz, kv.z));
            float d2 = __fsub_rn(__fadd_rn(qq, kv.w), __fmul_rn(2.0f, dot));
            bool adm = (d2 < bd[15]);
            if (adm) {
                int id = t0 + ii;
                cb_d[0] = (cnt == 0) ? d2 : cb_d[0]; cb_i[0] = (cnt == 0) ? id : cb_i[0];
                cb_d[1] = (cnt == 1) ? d2 : cb_d[1]; cb_i[1] = (cnt == 1) ? id : cb_i[1];
                cb_d[2] = (cnt == 2) ? d2 : cb_d[2]; cb_i[2] = (cnt == 2) ? id : cb_i[2];
                cb_d[3] = (cnt == 3) ? d2 : cb_d[3]; cb_i[3] = (cnt == 3) ? id : cb_i[3];
                ++cnt;
            }
            if (__any(cnt >= 4)) {
#pragma unroll
                for (int s = 0; s < 4; ++s) {
                    bool have = s < cnt;
                    float dv = have ? cb_d[s] : 3.4e38f;
                    int   iv = have ? cb_i[s] : 0;
                    KNN_INSERT(dv, iv)
                }
                cnt = 0;
            }
        }
        __syncthreads();
    }
#pragma unroll
    for (int s = 0; s < 4; ++s) {
        bool have = s < cnt;
        float dv = have ? cb_d[s] : 3.4e38f;
        int   iv = have ? cb_i[s] : 0;
        KNN_INSERT(dv, iv)
    }
#pragma unroll
    for (int j = 0; j < 16; ++j)
        u.k.mrg[wave][qloc][j] = make_float2(bd[j], __int_as_float(bi[j]));
    __syncthreads();

    if (tid < 64) {
        int qm = tid;
        int qg = (blockIdx.x - 1) * 64 + qm;
        int* op = idxout + (size_t)(b * N + qg) * 16;
        int p0 = 0, p1 = 0, p2 = 0, p3 = 0;
#pragma unroll 1
        for (int j = 0; j < 16; ++j) {
            float2 h0 = u.k.mrg[0][qm][p0], h1 = u.k.mrg[1][qm][p1];
            float2 h2 = u.k.mrg[2][qm][p2], h3 = u.k.mrg[3][qm][p3];
            float bdv = h0.x; int biv = __float_as_int(h0.y); int w_ = 0;
            int i1 = __float_as_int(h1.y);
            if (h1.x < bdv || (h1.x == bdv && i1 < biv)) { bdv = h1.x; biv = i1; w_ = 1; }
            int i2v = __float_as_int(h2.y);
            if (h2.x < bdv || (h2.x == bdv && i2v < biv)) { bdv = h2.x; biv = i2v; w_ = 2; }
            int i3 = __float_as_int(h3.y);
            if (h3.x < bdv || (h3.x == bdv && i3 < biv)) { bdv = h3.x; biv = i3; w_ = 3; }
            op[j] = biv;
            p0 += (w_ == 0); p1 += (w_ == 1); p2 += (w_ == 2); p3 += (w_ == 3);
        }
    }
}

// ---------------------------------------------------------------------------
// knn_kernel: standard (knn3, knn4).
// ---------------------------------------------------------------------------
__global__ __launch_bounds__(256) void knn_kernel(
    const float* __restrict__ qxyz, const float* __restrict__ kxyz,
    int* __restrict__ idxout, int Nq, int Nk)
{
    __shared__ float4 kt[256];
    __shared__ float2 mrg[4][64][16];
    int b = blockIdx.y;
    int qloc = threadIdx.x & 63;
    int wave = threadIdx.x >> 6;
    int q = blockIdx.x * 64 + qloc;
    bool act = q < Nq;

    float qx = 0.f, qy = 0.f, qz = 0.f, qq = 0.f;
    if (act) {
        const float* qp = qxyz + (size_t)(b * Nq + q) * 3;
        qx = qp[0]; qy = qp[1]; qz = qp[2];
        qq = __fadd_rn(__fadd_rn(__fmul_rn(qx, qx), __fmul_rn(qy, qy)), __fmul_rn(qz, qz));
    }
    float bd[16]; int bi[16];
#pragma unroll
    for (int j = 0; j < 16; ++j) { bd[j] = 3.4e38f; bi[j] = 0; }
    float cb_d[4]; int cb_i[4]; int cnt = 0;
#pragma unroll
    for (int s = 0; s < 4; ++s) { cb_d[s] = 3.4e38f; cb_i[s] = 0; }

    for (int t0 = 0; t0 < Nk; t0 += 256) {
        {
            int i = threadIdx.x;
            const float* kp = kxyz + (size_t)(b * Nk + t0 + i) * 3;
            float kx = kp[0], ky = kp[1], kz = kp[2];
            float kn = __fadd_rn(__fadd_rn(__fmul_rn(kx, kx), __fmul_rn(ky, ky)), __fmul_rn(kz, kz));
            kt[i] = make_float4(kx, ky, kz, kn);
        }
        __syncthreads();
        for (int i2 = 0; i2 < 64; ++i2) {
            int ii = wave * 64 + i2;
            float4 kv = kt[ii];
            float dot = __fadd_rn(__fadd_rn(__fmul_rn(qx, kv.x), __fmul_rn(qy, kv.y)),
                                  __fmul_rn(qz, kv.z));
            float d2 = __fsub_rn(__fadd_rn(qq, kv.w), __fmul_rn(2.0f, dot));
            bool adm = act && (d2 < bd[15]);
            if (adm) {
                int id = t0 + ii;
                cb_d[0] = (cnt == 0) ? d2 : cb_d[0]; cb_i[0] = (cnt == 0) ? id : cb_i[0];
                cb_d[1] = (cnt == 1) ? d2 : cb_d[1]; cb_i[1] = (cnt == 1) ? id : cb_i[1];
                cb_d[2] = (cnt == 2) ? d2 : cb_d[2]; cb_i[2] = (cnt == 2) ? id : cb_i[2];
                cb_d[3] = (cnt == 3) ? d2 : cb_d[3]; cb_i[3] = (cnt == 3) ? id : cb_i[3];
                ++cnt;
            }
            if (__any(cnt >= 4)) {
#pragma unroll
                for (int s = 0; s < 4; ++s) {
                    bool have = s < cnt;
                    float dv = have ? cb_d[s] : 3.4e38f;
                    int   iv = have ? cb_i[s] : 0;
                    KNN_INSERT(dv, iv)
                }
                cnt = 0;
            }
        }
        __syncthreads();
    }
#pragma unroll
    for (int s = 0; s < 4; ++s) {
        bool have = s < cnt;
        float dv = have ? cb_d[s] : 3.4e38f;
        int   iv = have ? cb_i[s] : 0;
        KNN_INSERT(dv, iv)
    }
#pragma unroll
    for (int j = 0; j < 16; ++j)
        mrg[wave][qloc][j] = make_float2(bd[j], __int_as_float(bi[j]));
    __syncthreads();

    if (threadIdx.x < 64) {
        int qm = threadIdx.x;
        int qg = blockIdx.x * 64 + qm;
        if (qg < Nq) {
            int* op = idxout + (size_t)(b * Nq + qg) * 16;
            int p0 = 0, p1 = 0, p2 = 0, p3 = 0;
#pragma unroll 1
            for (int j = 0; j < 16; ++j) {
                float2 h0 = mrg[0][qm][p0], h1 = mrg[1][qm][p1];
                float2 h2 = mrg[2][qm][p2], h3 = mrg[3][qm][p3];
                float bdv = h0.x; int biv = __float_as_int(h0.y); int w_ = 0;
                int i1 = __float_as_int(h1.y);
                if (h1.x < bdv || (h1.x == bdv && i1 < biv)) { bdv = h1.x; biv = i1; w_ = 1; }
                int i2v = __float_as_int(h2.y);
                if (h2.x < bdv || (h2.x == bdv && i2v < biv)) { bdv = h2.x; biv = i2v; w_ = 2; }
                int i3 = __float_as_int(h3.y);
                if (h3.x < bdv || (h3.x == bdv && i3 < biv)) { bdv = h3.x; biv = i3; w_ = 3; }
                op[j] = biv;
                p0 += (w_ == 0); p1 += (w_ == 1); p2 += (w_ == 2); p3 += (w_ == 3);
            }
        }
    }
}

// ---------------------------------------------------------------------------
// knn_part + merge (knn2 key-split x4).
// ---------------------------------------------------------------------------
__global__ __launch_bounds__(256) void knn_part_kernel(
    const float* __restrict__ qxyz, const float* __restrict__ kxyz,
    float2* __restrict__ pbuf, int Nq, int Nk, int nchunk)
{
    __shared__ float4 kt[256];
    __shared__ float2 mrg[4][64][16];
    int qblks = Nq / 64;
    int chunk = blockIdx.x / qblks;
    int qblk = blockIdx.x % qblks;
    int klen = Nk / nchunk;
    int klo = chunk * klen, khi = klo + klen;
    int b = blockIdx.y;
    int qloc = threadIdx.x & 63;
    int wave = threadIdx.x >> 6;
    int q = qblk * 64 + qloc;

    const float* qp = qxyz + (size_t)(b * Nq + q) * 3;
    float qx = qp[0], qy = qp[1], qz = qp[2];
    float qq = __fadd_rn(__fadd_rn(__fmul_rn(qx, qx), __fmul_rn(qy, qy)), __fmul_rn(qz, qz));
    float bd[16]; int bi[16];
#pragma unroll
    for (int j = 0; j < 16; ++j) { bd[j] = 3.4e38f; bi[j] = 0; }
    float cb_d[4]; int cb_i[4]; int cnt = 0;
#pragma unroll
    for (int s = 0; s < 4; ++s) { cb_d[s] = 3.4e38f; cb_i[s] = 0; }

    for (int t0 = klo; t0 < khi; t0 += 256) {
        {
            int i = threadIdx.x;
            const float* kp = kxyz + (size_t)(b * Nk + t0 + i) * 3;
            float kx = kp[0], ky = kp[1], kz = kp[2];
            float kn = __fadd_rn(__fadd_rn(__fmul_rn(kx, kx), __fmul_rn(ky, ky)), __fmul_rn(kz, kz));
            kt[i] = make_float4(kx, ky, kz, kn);
        }
        __syncthreads();
        for (int i2 = 0; i2 < 64; ++i2) {
            int ii = wave * 64 + i2;
            float4 kv = kt[ii];
            float dot = __fadd_rn(__fadd_rn(__fmul_rn(qx, kv.x), __fmul_rn(qy, kv.y)),
                                  __fmul_rn(qz, kv.z));
            float d2 = __fsub_rn(__fadd_rn(qq, kv.w), __fmul_rn(2.0f, dot));
            bool adm = (d2 < bd[15]);
            if (adm) {
                int id = t0 + ii;
                cb_d[0] = (cnt == 0) ? d2 : cb_d[0]; cb_i[0] = (cnt == 0) ? id : cb_i[0];
                cb_d[1] = (cnt == 1) ? d2 : cb_d[1]; cb_i[1] = (cnt == 1) ? id : cb_i[1];
                cb_d[2] = (cnt == 2) ? d2 : cb_d[2]; cb_i[2] = (cnt == 2) ? id : cb_i[2];
                cb_d[3] = (cnt == 3) ? d2 : cb_d[3]; cb_i[3] = (cnt == 3) ? id : cb_i[3];
                ++cnt;
            }
            if (__any(cnt >= 4)) {
#pragma unroll
                for (int s = 0; s < 4; ++s) {
                    bool have = s < cnt;
                    float dv = have ? cb_d[s] : 3.4e38f;
                    int   iv = have ? cb_i[s] : 0;
                    KNN_INSERT(dv, iv)
                }
                cnt = 0;
            }
        }
        __syncthreads();
    }
#pragma unroll
    for (int s = 0; s < 4; ++s) {
        bool have = s < cnt;
        float dv = have ? cb_d[s] : 3.4e38f;
        int   iv = have ? cb_i[s] : 0;
        KNN_INSERT(dv, iv)
    }
#pragma unroll
    for (int j = 0; j < 16; ++j)
        mrg[wave][qloc][j] = make_float2(bd[j], __int_as_float(bi[j]));
    __syncthreads();

    if (threadIdx.x < 64) {
        int qm = threadIdx.x;
        int qg = qblk * 64 + qm;
        float2* op = pbuf + (((size_t)(b * Nq + qg) * nchunk) + chunk) * 16;
        int p0 = 0, p1 = 0, p2 = 0, p3 = 0;
#pragma unroll 1
        for (int j = 0; j < 16; ++j) {
            float2 h0 = mrg[0][qm][p0], h1 = mrg[1][qm][p1];
            float2 h2 = mrg[2][qm][p2], h3 = mrg[3][qm][p3];
            float bdv = h0.x; int biv = __float_as_int(h0.y); int w_ = 0;
            int i1 = __float_as_int(h1.y);
            if (h1.x < bdv || (h1.x == bdv && i1 < biv)) { bdv = h1.x; biv = i1; w_ = 1; }
            int i2v = __float_as_int(h2.y);
            if (h2.x < bdv || (h2.x == bdv && i2v < biv)) { bdv = h2.x; biv = i2v; w_ = 2; }
            int i3 = __float_as_int(h3.y);
            if (h3.x < bdv || (h3.x == bdv && i3 < biv)) { bdv = h3.x; biv = i3; w_ = 3; }
            op[j] = make_float2(bdv, __int_as_float(biv));
            p0 += (w_ == 0); p1 += (w_ == 1); p2 += (w_ == 2); p3 += (w_ == 3);
        }
    }
}

__global__ void knn_merge_kernel(const float2* __restrict__ pbuf, int* __restrict__ idxout,
                                 int total)
{
    int q = blockIdx.x * 256 + threadIdx.x;
    if (q >= total) return;
    const float2* L = pbuf + (size_t)q * 64;
    int* op = idxout + (size_t)q * 16;
    int p0 = 0, p1 = 0, p2 = 0, p3 = 0;
#pragma unroll 1
    for (int j = 0; j < 16; ++j) {
        float2 h0 = L[p0], h1 = L[16 + p1], h2 = L[32 + p2], h3 = L[48 + p3];
        float bdv = h0.x; int biv = __float_as_int(h0.y); int w_ = 0;
        int i1 = __float_as_int(h1.y);
        if (h1.x < bdv || (h1.x == bdv && i1 < biv)) { bdv = h1.x; biv = i1; w_ = 1; }
        int i2v = __float_as_int(h2.y);
        if (h2.x < bdv || (h2.x == bdv && i2v < biv)) { bdv = h2.x; biv = i2v; w_ = 2; }
        int i3 = __float_as_int(h3.y);
        if (h3.x < bdv || (h3.x == bdv && i3 < biv)) { bdv = h3.x; biv = i3; w_ = 3; }
        op[j] = biv;
        p0 += (w_ == 0); p1 += (w_ == 1); p2 += (w_ == 2); p3 += (w_ == 3);
    }
}

// ---------------------------------------------------------------------------
// 5-payload DPP reduce (fps_solo role).
// ---------------------------------------------------------------------------
template<int CTRL>
DEV void red5(float& v, int& i, float& x, float& y, float& z)
{
    float ov = __int_as_float(__builtin_amdgcn_update_dpp(
        __float_as_int(v), __float_as_int(v), CTRL, 0xf, 0xf, false));
    int oi = __builtin_amdgcn_update_dpp(i, i, CTRL, 0xf, 0xf, false);
    float ox = __int_as_float(__builtin_amdgcn_update_dpp(
        __float_as_int(x), __float_as_int(x), CTRL, 0xf, 0xf, false));
    float oy = __int_as_float(__builtin_amdgcn_update_dpp(
        __float_as_int(y), __float_as_int(y), CTRL, 0xf, 0xf, false));
    float oz = __int_as_float(__builtin_amdgcn_update_dpp(
        __float_as_int(z), __float_as_int(z), CTRL, 0xf, 0xf, false));
    bool t = (ov > v) || (ov == v && oi < i);
    v = t ? ov : v; i = t ? oi : i; x = t ? ox : x; y = t ? oy : y; z = t ? oz : z;
}

// ---------------------------------------------------------------------------
// stats3_fps: blockIdx.x==0 -> fps_solo<8,512> role (setprio 3); x>=1 ->
// edge_conv_stats<64,64> with chunk = x-1.
// ---------------------------------------------------------------------------
template<bool STORE_V>
__global__ __launch_bounds__(256) void stats3_fps_kernel(
    const float* __restrict__ fq, const float* __restrict__ fk, const int* __restrict__ idx,
    const float* __restrict__ w, float* __restrict__ partials, float* __restrict__ vbuf,
    const float* __restrict__ fxyz, int* __restrict__ fpsout, int Nq, int Nk)
{
    constexpr int K = 16, C_IN = 64, C_OUT = 64, E = 2 * C_IN, GC = C_OUT / 4;
    __shared__ alignas(16) float edge[4][K][E];
    __shared__ int nidx[4][K];
    __shared__ float gsum[4][4][2];

    int b = blockIdx.y;
    if (blockIdx.x == 0) {
        int tid = threadIdx.x;
        if (tid >= 64) return;
        __builtin_amdgcn_s_setprio(3);
        constexpr int PTS = 8, NL = 512;
        float px[PTS], py[PTS], pz[PTS], dist[PTS];
#pragma unroll
        for (int i = 0; i < PTS; ++i) {
            int p = tid + i * 64;
            const float* pp = fxyz + (size_t)(b * NL + p) * 3;
            px[i] = pp[0]; py[i] = pp[1]; pz[i] = pp[2];
            dist[i] = 1e10f;
        }
        float cx = __int_as_float(__builtin_amdgcn_readlane(__float_as_int(px[0]), 0));
        float cy = __int_as_float(__builtin_amdgcn_readlane(__float_as_int(py[0]), 0));
        float cz = __int_as_float(__builtin_amdgcn_readlane(__float_as_int(pz[0]), 0));
        int curidx = 0;
        int my0 = 0, my1 = 0;
        for (int it = 0; it < 128; ++it) {
            if (it == tid)      my0 = curidx;
            if (it == tid + 64) my1 = curidx;
            float bv = -1.f; int bid = 0; float bx = 0.f, by = 0.f, bz = 0.f;
#pragma unroll
            for (int i = 0; i < PTS; ++i) {
                float dx = __fsub_rn(px[i], cx);
                float dy = __fsub_rn(py[i], cy);
                float dz = __fsub_rn(pz[i], cz);
                float d = __fadd_rn(__fadd_rn(__fmul_rn(dx, dx), __fmul_rn(dy, dy)), __fmul_rn(dz, dz));
                float nd = fminf(dist[i], d);
                dist[i] = nd;
                bool t = nd > bv;
                bv = t ? nd : bv; bid = t ? (tid + i * 64) : bid;
                bx = t ? px[i] : bx; by = t ? py[i] : by; bz = t ? pz[i] : bz;
            }
            red5<0x0B1>(bv, bid, bx, by, bz);
            red5<0x04E>(bv, bid, bx, by, bz);
            red5<0x124>(bv, bid, bx, by, bz);
            red5<0x128>(bv, bid, bx, by, bz);
            red5<0x142>(bv, bid, bx, by, bz);
            red5<0x143>(bv, bid, bx, by, bz);
            curidx = __builtin_amdgcn_readlane(bid, 63);
            cx = __int_as_float(__builtin_amdgcn_readlane(__float_as_int(bx), 63));
            cy = __int_as_float(__builtin_amdgcn_readlane(__float_as_int(by), 63));
            cz = __int_as_float(__builtin_amdgcn_readlane(__float_as_int(bz), 63));
        }
        __builtin_amdgcn_s_setprio(0);
        if (tid < 128)      fpsout[b * 128 + tid] = my0;
        if (tid + 64 < 128) fpsout[b * 128 + tid + 64] = my1;
        return;
    }

    int wave = threadIdx.x >> 6, lane = threadIdx.x & 63;
    int nqc = Nq >> 2;
    int chunk = blockIdx.x - 1;
    int q = chunk * 4 + wave;

    const float* xqr = fq + (size_t)(b * Nq + q) * C_IN;
    if (lane < K) nidx[wave][lane] = idx[(size_t)(b * Nq + q) * K + lane];
    for (int t = lane; t < K * E; t += 64) {
        int k = t / E, c = t % E;
        int j = nidx[wave][k];
        float v;
        if (c < C_IN) v = fk[(size_t)(b * Nk + j) * C_IN + c] - xqr[c];
        else          v = xqr[c - C_IN];
        edge[wave][k][c] = v;
    }
    __syncthreads();

    {
        int oc = lane;
        float s = 0.f, ss = 0.f;
        float v[K];
#pragma unroll
        for (int k2 = 0; k2 < K; ++k2) v[k2] = 0.f;
        const float* wr = w + (size_t)oc * E;
        for (int c = 0; c < E; c += 4) {
            float4 wv = *reinterpret_cast<const float4*>(wr + c);
#pragma unroll
            for (int k2 = 0; k2 < K; ++k2) {
                const float4 e4 = *reinterpret_cast<const float4*>(&edge[wave][k2][c]);
                v[k2] = fmaf(wv.x, e4.x, v[k2]);
                v[k2] = fmaf(wv.y, e4.y, v[k2]);
                v[k2] = fmaf(wv.z, e4.z, v[k2]);
                v[k2] = fmaf(wv.w, e4.w, v[k2]);
            }
        }
        if (STORE_V) {
            float4* vb = (float4*)(vbuf + ((size_t)(b * Nq + q) * C_OUT + oc) * 16);
            vb[0] = make_float4(v[0], v[1], v[2], v[3]);
            vb[1] = make_float4(v[4], v[5], v[6], v[7]);
            vb[2] = make_float4(v[8], v[9], v[10], v[11]);
            vb[3] = make_float4(v[12], v[13], v[14], v[15]);
        }
#pragma unroll
        for (int k2 = 0; k2 < K; ++k2) { s += v[k2]; ss = fmaf(v[k2], v[k2], ss); }
#pragma unroll
        for (int m2 = 1; m2 < GC; m2 <<= 1) { s += __shfl_xor(s, m2); ss += __shfl_xor(ss, m2); }
        if ((oc & (GC - 1)) == 0) {
            gsum[wave][oc / GC][0] = s; gsum[wave][oc / GC][1] = ss;
        }
    }
    __syncthreads();
    if (threadIdx.x < 4) {
        int g = threadIdx.x;
        float s  = ((gsum[0][g][0] + gsum[1][g][0]) + gsum[2][g][0]) + gsum[3][g][0];
        float ss = ((gsum[0][g][1] + gsum[1][g][1]) + gsum[2][g][1]) + gsum[3][g][1];
        size_t pi = ((size_t)(b * 4 + g) * nqc + chunk) * 2;
        partials[pi] = s; partials[pi + 1] = ss;
    }
}

// ---------------------------------------------------------------------------
__global__ void gather_kernel(const float* __restrict__ coorS, const float* __restrict__ fS,
                              const int* __restrict__ fidx, float* __restrict__ coorD,
                              float* __restrict__ fD, int Ns, int M, int C)
{
    int b = blockIdx.y;
    int m = blockIdx.x * blockDim.x + threadIdx.x;
    if (m >= M) return;
    int j = fidx[b * M + m];
#pragma unroll
    for (int c = 0; c < 3; ++c)
        coorD[((size_t)b * M + m) * 3 + c] = coorS[((size_t)b * Ns + j) * 3 + c];
    for (int c = 0; c < C; ++c)
        fD[((size_t)b * M + m) * C + c] = fS[((size_t)b * Ns + j) * C + c];
}

// ---------------------------------------------------------------------------
// edge-conv stats (stages 1, 2, 4 + fallbacks).
// ---------------------------------------------------------------------------
template<int C_IN, int C_OUT, bool STORE_V>
__global__ __launch_bounds__(256) void edge_conv_stats_t(
    const float* __restrict__ fq, const float* __restrict__ fk, const int* __restrict__ idx,
    const float* __restrict__ w, float* __restrict__ partials, float* __restrict__ vbuf,
    int Nq, int Nk)
{
    constexpr int K = 16, E = 2 * C_IN, GC = C_OUT / 4;
    constexpr int ITERS = (C_OUT + 63) / 64;
    __shared__ alignas(16) float edge[4][K][E];
    __shared__ int nidx[4][K];
    __shared__ float gsum[4][4][2];

    int wave = threadIdx.x >> 6, lane = threadIdx.x & 63;
    int nqc = Nq >> 2;
    int b = blockIdx.y, chunk = blockIdx.x;
    int q = chunk * 4 + wave;

    const float* xqr = fq + (size_t)(b * Nq + q) * C_IN;
    if (lane < K) nidx[wave][lane] = idx[(size_t)(b * Nq + q) * K + lane];
    for (int t = lane; t < K * E; t += 64) {
        int k = t / E, c = t % E;
        int j = nidx[wave][k];
        float v;
        if (c < C_IN) v = fk[(size_t)(b * Nk + j) * C_IN + c] - xqr[c];
        else          v = xqr[c - C_IN];
        edge[wave][k][c] = v;
    }
    __syncthreads();

#pragma unroll
    for (int itr = 0; itr < ITERS; ++itr) {
        int oc = lane + 64 * itr;
        float s = 0.f, ss = 0.f;
        if (oc < C_OUT) {
            float v[K];
#pragma unroll
            for (int k2 = 0; k2 < K; ++k2) v[k2] = 0.f;
            const float* wr = w + (size_t)oc * E;
            for (int c = 0; c < E; c += 4) {
                float4 wv = *reinterpret_cast<const float4*>(wr + c);
#pragma unroll
                for (int k2 = 0; k2 < K; ++k2) {
                    const float4 e4 = *reinterpret_cast<const float4*>(&edge[wave][k2][c]);
                    v[k2] = fmaf(wv.x, e4.x, v[k2]);
                    v[k2] = fmaf(wv.y, e4.y, v[k2]);
                    v[k2] = fmaf(wv.z, e4.z, v[k2]);
                    v[k2] = fmaf(wv.w, e4.w, v[k2]);
                }
            }
            if (STORE_V) {
                float4* vb = (float4*)(vbuf + ((size_t)(b * Nq + q) * C_OUT + oc) * 16);
                vb[0] = make_float4(v[0], v[1], v[2], v[3]);
                vb[1] = make_float4(v[4], v[5], v[6], v[7]);
                vb[2] = make_float4(v[8], v[9], v[10], v[11]);
                vb[3] = make_float4(v[12], v[13], v[14], v[15]);
            }
#pragma unroll
            for (int k2 = 0; k2 < K; ++k2) { s += v[k2]; ss = fmaf(v[k2], v[k2], ss); }
        }
#pragma unroll
        for (int m2 = 1; m2 < GC; m2 <<= 1) { s += __shfl_xor(s, m2); ss += __shfl_xor(ss, m2); }
        if (oc < C_OUT && (oc & (GC - 1)) == 0) {
            gsum[wave][oc / GC][0] = s; gsum[wave][oc / GC][1] = ss;
        }
    }
    __syncthreads();
    if (threadIdx.x < 4) {
        int g = threadIdx.x;
        float s  = ((gsum[0][g][0] + gsum[1][g][0]) + gsum[2][g][0]) + gsum[3][g][0];
        float ss = ((gsum[0][g][1] + gsum[1][g][1]) + gsum[2][g][1]) + gsum[3][g][1];
        size_t pi = ((size_t)(b * 4 + g) * nqc + chunk) * 2;
        partials[pi] = s; partials[pi + 1] = ss;
    }
}

__global__ void gn_finalize(const float* __restrict__ partials, float* __restrict__ stats,
                            int nchunk, float inv_cnt)
{
    int i = threadIdx.x >> 3;
    int sl = threadIdx.x & 7;
    float s = 0.f, ss = 0.f;
    for (int c = sl; c < nchunk; c += 8) {
        s  += partials[((size_t)i * nchunk + c) * 2];
        ss += partials[((size_t)i * nchunk + c) * 2 + 1];
    }
#pragma unroll
    for (int m = 1; m < 8; m <<= 1) { s += __shfl_xor(s, m); ss += __shfl_xor(ss, m); }
    if (sl == 0) {
        float mean = s * inv_cnt;
        float var = fmaf(-mean, mean, ss * inv_cnt);
        stats[i * 2] = mean;
        stats[i * 2 + 1] = 1.0f / sqrtf(var + 1e-5f);
    }
}

// ---------------------------------------------------------------------------
// apply (fallback: recompute conv).
// ---------------------------------------------------------------------------
template<int C_IN, int C_OUT>
__global__ __launch_bounds__(256) void edge_conv_apply(
    const float* __restrict__ fq, const float* __restrict__ fk, const int* __restrict__ idx,
    const float* __restrict__ stats, const float* __restrict__ w,
    const float* __restrict__ gamma, const float* __restrict__ beta,
    float* __restrict__ outp, int Nq, int Nk)
{
    constexpr int K = 16, E = 2 * C_IN, GC = C_OUT / 4;
    constexpr int ITERS = (C_OUT + 63) / 64;
    __shared__ alignas(16) float edge[4][K][E];
    __shared__ int nidx[4][K];

    int wave = threadIdx.x >> 6, lane = threadIdx.x & 63;
    int b = blockIdx.y, chunk = blockIdx.x;
    int q = chunk * 4 + wave;

    const float* xqr = fq + (size_t)(b * Nq + q) * C_IN;
    if (lane < K) nidx[wave][lane] = idx[(size_t)(b * Nq + q) * K + lane];
    for (int t = lane; t < K * E; t += 64) {
        int k = t / E, c = t % E;
        int j = nidx[wave][k];
        float v;
        if (c < C_IN) v = fk[(size_t)(b * Nk + j) * C_IN + c] - xqr[c];
        else          v = xqr[c - C_IN];
        edge[wave][k][c] = v;
    }
    __syncthreads();

#pragma unroll
    for (int itr = 0; itr < ITERS; ++itr) {
        int oc = lane + 64 * itr;
        if (oc < C_OUT) {
            float v[K];
#pragma unroll
            for (int k2 = 0; k2 < K; ++k2) v[k2] = 0.f;
            const float* wr = w + (size_t)oc * E;
            for (int c = 0; c < E; c += 4) {
                float4 wv = *reinterpret_cast<const float4*>(wr + c);
#pragma unroll
                for (int k2 = 0; k2 < K; ++k2) {
                    const float4 e4 = *reinterpret_cast<const float4*>(&edge[wave][k2][c]);
                    v[k2] = fmaf(wv.x, e4.x, v[k2]);
                    v[k2] = fmaf(wv.y, e4.y, v[k2]);
                    v[k2] = fmaf(wv.z, e4.z, v[k2]);
                    v[k2] = fmaf(wv.w, e4.w, v[k2]);
                }
            }
            int g = oc / GC;
            float mean = stats[(b * 4 + g) * 2 + 0];
            float rstd = stats[(b * 4 + g) * 2 + 1];
            float ga = gamma[oc], be = beta[oc];
            float m = -3.4e38f;
#pragma unroll
            for (int k2 = 0; k2 < K; ++k2) {
                float y = fmaf((v[k2] - mean) * rstd, ga, be);
                y = (y >= 0.f) ? y : 0.2f * y;
                m = fmaxf(m, y);
            }
            outp[(size_t)(b * Nq + q) * C_OUT + oc] = m;
        }
    }
}

// ---------------------------------------------------------------------------
template<int C_OUT>
__global__ __launch_bounds__(256) void edge_conv_apply2(
    const float* __restrict__ vbuf, const float* __restrict__ stats,
    const float* __restrict__ gamma, const float* __restrict__ beta,
    float* __restrict__ outp, int total, int Nq)
{
    constexpr int GC = C_OUT / 4;
    int t = blockIdx.x * 256 + threadIdx.x;
    if (t >= total) return;
    int oc = t & (C_OUT - 1);
    int bq = t / C_OUT;
    int b = bq / Nq;
    int g = oc / GC;
    float mean = stats[(b * 4 + g) * 2 + 0];
    float rstd = stats[(b * 4 + g) * 2 + 1];
    float ga = gamma[oc], be = beta[oc];
    const float4* vb = (const float4*)(vbuf + (size_t)t * 16);
    float m = -3.4e38f;
#pragma unroll
    for (int j = 0; j < 4; ++j) {
        float4 v4 = vb[j];
        float y;
        y = fmaf((v4.x - mean) * rstd, ga, be); y = (y >= 0.f) ? y : 0.2f * y; m = fmaxf(m, y);
        y = fmaf((v4.y - mean) * rstd, ga, be); y = (y >= 0.f) ? y : 0.2f * y; m = fmaxf(m, y);
        y = fmaf((v4.z - mean) * rstd, ga, be); y = (y >= 0.f) ? y : 0.2f * y; m = fmaxf(m, y);
        y = fmaf((v4.w - mean) * rstd, ga, be); y = (y >= 0.f) ? y : 0.2f * y; m = fmaxf(m, y);
    }
    outp[t] = m;
}

// ---------------------------------------------------------------------------
__global__ __launch_bounds__(256) void apply2_out(
    const float* __restrict__ vbuf, const float* __restrict__ stats,
    const float* __restrict__ gamma, const float* __restrict__ beta,
    const float* __restrict__ coor2T, void* __restrict__ outv,
    const int* __restrict__ flag)
{
    int t = blockIdx.x * 256 + threadIdx.x;
    int isbf = flag[0];
    if (t < 131072) {
        int oc = t & 127;
        int bq = t >> 7;
        int b = bq >> 7;
        int q = bq & 127;
        int g = oc >> 5;
        float mean = stats[(b * 4 + g) * 2 + 0];
        float rstd = stats[(b * 4 + g) * 2 + 1];
        float ga = gamma[oc], be = beta[oc];
        const float4* vb = (const float4*)(vbuf + (size_t)t * 16);
        float m = -3.4e38f;
#pragma unroll
        for (int j = 0; j < 4; ++j) {
            float4 v4 = vb[j];
            float y;
            y = fmaf((v4.x - mean) * rstd, ga, be); y = (y >= 0.f) ? y : 0.2f * y; m = fmaxf(m, y);
            y = fmaf((v4.y - mean) * rstd, ga, be); y = (y >= 0.f) ? y : 0.2f * y; m = fmaxf(m, y);
            y = fmaf((v4.z - mean) * rstd, ga, be); y = (y >= 0.f) ? y : 0.2f * y; m = fmaxf(m, y);
            y = fmaf((v4.w - mean) * rstd, ga, be); y = (y >= 0.f) ? y : 0.2f * y; m = fmaxf(m, y);
        }
        int i = 3072 + b * 16384 + oc * 128 + q;
        if (isbf) ((u16*)outv)[i] = f2bf(m);
        else      ((float*)outv)[i] = m;
    } else if (t < 134144) {
        int i = t - 131072;
        int b = i / 384, r = i % 384;
        int c = r / 128, n = r % 128;
        float v = coor2T[((size_t)b * 128 + n) * 3 + c];
        if (isbf) ((u16*)outv)[i] = f2bf(v);
        else      ((float*)outv)[i] = v;
    }
}

// ---------------------------------------------------------------------------
__global__ void write_out_kernel(const float* __restrict__ coor2T, const float* __restrict__ f4T,
                                 void* __restrict__ outv, const int* __restrict__ flag)
{
    int i = blockIdx.x * blockDim.x + threadIdx.x;
    if (i >= 134144) return;
    float v;
    if (i < 3072) {
        int b = i / 384, r = i % 384;
        int c = r / 128, n = r % 128;
        v = coor2T[((size_t)b * 128 + n) * 3 + c];
    } else {
        int jj = i - 3072;
        int b = jj / 16384, r = jj % 16384;
        int c = r / 128, qn = r % 128;
        v = f4T[((size_t)b * 128 + qn) * 128 + c];
    }
    if (flag[0]) ((u16*)outv)[i] = f2bf(v);
    else         ((float*)outv)[i] = v;
}

// ---------------------------------------------------------------------------
extern "C" void kernel_launch(void* const* d_in, const int* in_sizes, int n_in,
                              void* d_out, int out_size, void* d_ws, size_t ws_size,
                              hipStream_t stream)
{
    (void)in_sizes; (void)n_in; (void)out_size;
    constexpr int B = 8, N = 4096, M1 = 512, M2 = 128;

    float* fbase   = (float*)d_ws;
    float* coorT   = fbase;                  // 98304
    float* f0T     = coorT + 98304;          // 262144
    float* f1T     = f0T + 262144;           // 1048576
    float* f2T     = f1T + 1048576;          // 262144
    float* f3T     = f2T + 262144;           // 262144
    float* f4T     = f3T + 262144;           // 131072
    float* coor1T  = f4T + 131072;           // 12288
    float* coor2T  = coor1T + 12288;         // 3072
    float* fq2T    = coor2T + 3072;          // 131072
    float* fq4T    = fq2T + 131072;          // 65536
    float* statsb  = fq4T + 65536;           // 256
    float* partials= statsb + 256;           // 65536
    float* pb      = partials + 65536;       // 524288
    float* cw      = pb + 524288;            // 29792 (+pad)
    int* ibase = (int*)(cw + 29796);
    int* idx1 = ibase;                       // 524288
    int* idx2 = idx1 + 524288;               // 65536
    int* idx3 = idx2 + 65536;                // 65536
    int* idx4 = idx3 + 65536;                // 16384
    int* fps1 = idx4 + 16384;                // 4096
    int* fps2 = fps1 + 4096;                 // 1024
    int* flag = fps2 + 1024;                 // 1

    size_t used = (size_t)((char*)(flag + 1) - (char*)d_ws);
    size_t voff = (used + 255) & ~(size_t)255;
    float* vbuf = (float*)((char*)d_ws + voff);
    bool fu1 = ws_size >= voff + (size_t)16777216 * 4;
    bool fu2 = ws_size >= voff + (size_t)4194304 * 4;
    bool fu3 = fu2;
    bool fu4 = ws_size >= voff + (size_t)2097152 * 4;

    const float* w1c  = cw + 32;
    const float* g1c  = cw + 544;
    const float* be1c = cw + 576;
    const float* w2c  = cw + 608;
    const float* g2c  = cw + 4704;
    const float* be2c = cw + 4768;
    const float* w3c  = cw + 4832;
    const float* g3c  = cw + 13024;
    const float* be3c = cw + 13088;
    const float* w4c  = cw + 13152;
    const float* g4c  = cw + 29536;
    const float* be4c = cw + 29664;

    InPtrs ptrs;
    for (int i = 0; i < 14; ++i) ptrs.p[i] = d_in[i + 2];

    fused_prep<<<245, 256, 0, stream>>>(d_in[0], ptrs, cw, coorT, f0T, flag, B, N);

    // stage 1: knn1 || fps_big in one launch (fps blocks at x==0, setprio 3)
    knn_fps_kernel<4096, 16><<<dim3(N / 64 + 1, B), 256, 0, stream>>>(coorT, idx1, fps1, M1);
    if (fu1) {
        edge_conv_stats_t<8, 32, true><<<dim3(N / 4, B), 256, 0, stream>>>(f0T, f0T, idx1, w1c, partials, vbuf, N, N);
        gn_finalize<<<1, 256, 0, stream>>>(partials, statsb + 0, N / 4, 1.0f / (float)(N * 16 * 8));
        edge_conv_apply2<32><<<(B * N * 32 + 255) / 256, 256, 0, stream>>>(vbuf, statsb + 0, g1c, be1c, f1T, B * N * 32, N);
    } else {
        edge_conv_stats_t<8, 32, false><<<dim3(N / 4, B), 256, 0, stream>>>(f0T, f0T, idx1, w1c, partials, vbuf, N, N);
        gn_finalize<<<1, 256, 0, stream>>>(partials, statsb + 0, N / 4, 1.0f / (float)(N * 16 * 8));
        edge_conv_apply<8, 32><<<dim3(N / 4, B), 256, 0, stream>>>(f0T, f0T, idx1, statsb + 0, w1c, g1c, be1c, f1T, N, N);
    }
    gather_kernel<<<dim3((M1 + 255) / 256, B), 256, 0, stream>>>(coorT, f1T, fps1, coor1T, fq2T, N, M1, 32);

    // stage 2: knn2 split into 4 key-chunks + merge
    knn_part_kernel<<<dim3((M1 / 64) * 4, B), 256, 0, stream>>>(coor1T, coorT, (float2*)pb, M1, N, 4);
    knn_merge_kernel<<<(B * M1 + 255) / 256, 256, 0, stream>>>((const float2*)pb, idx2, B * M1);
    if (fu2) {
        edge_conv_stats_t<32, 64, true><<<dim3(M1 / 4, B), 256, 0, stream>>>(fq2T, f1T, idx2, w2c, partials, vbuf, M1, N);
        gn_finalize<<<1, 256, 0, stream>>>(partials, statsb + 64, M1 / 4, 1.0f / (float)(M1 * 16 * 16));
        edge_conv_apply2<64><<<(B * M1 * 64 + 255) / 256, 256, 0, stream>>>(vbuf, statsb + 64, g2c, be2c, f2T, B * M1 * 64, M1);
    } else {
        edge_conv_stats_t<32, 64, false><<<dim3(M1 / 4, B), 256, 0, stream>>>(fq2T, f1T, idx2, w2c, partials, vbuf, M1, N);
        gn_finalize<<<1, 256, 0, stream>>>(partials, statsb + 64, M1 / 4, 1.0f / (float)(M1 * 16 * 16));
        edge_conv_apply<32, 64><<<dim3(M1 / 4, B), 256, 0, stream>>>(fq2T, f1T, idx2, statsb + 64, w2c, g2c, be2c, f2T, M1, N);
    }

    // stage 3: knn3, then stats3 || fps_solo (setprio 3)
    knn_kernel<<<dim3(M1 / 64, B), 256, 0, stream>>>(coor1T, coor1T, idx3, M1, M1);
    if (fu3) {
        stats3_fps_kernel<true><<<dim3(M1 / 4 + 1, B), 256, 0, stream>>>(
            f2T, f2T, idx3, w3c, partials, vbuf, coor1T, fps2, M1, M1);
        gn_finalize<<<1, 256, 0, stream>>>(partials, statsb + 128, M1 / 4, 1.0f / (float)(M1 * 16 * 16));
        edge_conv_apply2<64><<<(B * M1 * 64 + 255) / 256, 256, 0, stream>>>(vbuf, statsb + 128, g3c, be3c, f3T, B * M1 * 64, M1);
    } else {
        stats3_fps_kernel<false><<<dim3(M1 / 4 + 1, B), 256, 0, stream>>>(
            f2T, f2T, idx3, w3c, partials, vbuf, coor1T, fps2, M1, M1);
        gn_finalize<<<1, 256, 0, stream>>>(partials, statsb + 128, M1 / 4, 1.0f / (float)(M1 * 16 * 16));
        edge_conv_apply<64, 64><<<dim3(M1 / 4, B), 256, 0, stream>>>(f2T, f2T, idx3, statsb + 128, w3c, g3c, be3c, f3T, M1, M1);
    }
    gather_kernel<<<dim3(1, B), 256, 0, stream>>>(coor1T, f3T, fps2, coor2T, fq4T, M1, M2, 64);

    // stage 4
    knn_kernel<<<dim3((M2 + 63) / 64, B), 256, 0, stream>>>(coor2T, coor1T, idx4, M2, M1);
    if (fu4) {
        edge_conv_stats_t<64, 128, true><<<dim3(M2 / 4, B), 256, 0, stream>>>(fq4T, f3T, idx4, w4c, partials, vbuf, M2, M1);
        gn_finalize<<<1, 256, 0, stream>>>(partials, statsb + 192, M2 / 4, 1.0f / (float)(M2 * 16 * 32));
        apply2_out<<<(134144 + 255) / 256, 256, 0, stream>>>(vbuf, statsb + 192, g4c, be4c, coor2T, d_out, flag);
    } else {
        edge_conv_stats_t<64, 128, false><<<dim3(M2 / 4, B), 256, 0, stream>>>(fq4T, f3T, idx4, w4c, partials, vbuf, M2, M1);
        gn_finalize<<<1, 256, 0, stream>>>(partials, statsb + 192, M2 / 4, 1.0f / (float)(M2 * 16 * 32));
        edge_conv_apply<64, 128><<<dim3(M2 / 4, B), 256, 0, stream>>>(fq4T, f3T, idx4, statsb + 192, w4c, g4c, be4c, f4T, M2, M1);
        write_out_kernel<<<(134144 + 255) / 256, 256, 0, stream>>>(coor2T, f4T, d_out, flag);
    }
}